// Round 14
// baseline (740.715 us; speedup 1.0000x reference)
//
#include <hip/hip_runtime.h>
#include <hip/hip_bf16.h>

#define NN 30000
#define NE 480000
#define NH 4
#define DH 64
#define MF 30
#define KG 10
#define RATIO 0.18257418583505536f   /* 1/sqrt(30) */
#define DNRM  0.35355339059327373f   /* 64^-0.25  */

// fp32 params block layout (element offsets)
#define P_WF    0        /* [768][256] Wq|Wk|Wv rows */
#define P_BF    196608   /* [768] bq|bk|bv */
#define P_WOF   197376   /* [64][256] Wo */
#define P_WOBF  213760   /* [64] Wo bias */
#define P_BBF   213824   /* [4] rb bias b */
#define P_PROJ  213828   /* [30][64] proj */
#define P_TAU   215748   /* scalar */
#define P_TOTAL 215749

typedef unsigned short u16;
typedef unsigned int   u32;
typedef __attribute__((ext_vector_type(8))) short bf16x8;
typedef __attribute__((ext_vector_type(4))) float f32x4;

__device__ __forceinline__ float u2f(u16 u) { return __uint_as_float(((u32)u) << 16); }
__device__ __forceinline__ u16  f2bf(float f) {  // round-to-nearest-even bf16
    u32 x = __float_as_uint(f);
    return (u16)((x + 0x7FFFu + ((x >> 16) & 1u)) >> 16);
}
// order-preserving float->uint encoding for atomicMax over signed floats
__device__ __forceinline__ u32  encf(float f) { u32 u = __float_as_uint(f); return (u & 0x80000000u) ? ~u : (u | 0x80000000u); }
__device__ __forceinline__ float decf(u32 u)  { return (u & 0x80000000u) ? __uint_as_float(u & 0x7FFFFFFFu) : __uint_as_float(~u); }

// ---------------- dtype detection (fp32 vs bf16 input tensors) ----------------
__global__ void k_detect(const u16* __restrict__ z, int* __restrict__ flag) {
    if (threadIdx.x == 0 && blockIdx.x == 0) {
        int bad = 0;
        for (int i = 0; i < 256; i += 2) {
            u16 u = z[i];
            int e = (u >> 7) & 0xFF;
            if (u != 0 && !(e >= 100 && e <= 140)) bad++;
        }
        *flag = (bad > 16) ? 1 : 0;   // 1 = inputs are fp32
    }
}

// ---------------- stage all small params to fp32 ----------------
__global__ __launch_bounds__(256) void k_cvt_params(
    const void* Wq, const void* Wk, const void* Wv,
    const void* bq, const void* bk, const void* bv,
    const void* Wo, const void* Wob, const void* bb, const void* proj,
    const void* taup, float* __restrict__ params, const int* __restrict__ flag)
{
    int i = blockIdx.x * 256 + threadIdx.x;
    if (i >= P_TOTAL) return;
    int f = *flag;
    if (i == P_TAU) {
        float v = f ? ((const float*)taup)[0] : u2f(((const u16*)taup)[0]);
        if (!(v > 1e-6f && v < 1e6f)) {
            float ff = ((const float*)taup)[0];
            v = (ff > 1e-6f && ff < 1e6f) ? ff : 0.25f;
        }
        params[i] = v;
        return;
    }
    const void* src; int j;
    if      (i < 65536)  { src = Wq;  j = i; }
    else if (i < 131072) { src = Wk;  j = i - 65536; }
    else if (i < 196608) { src = Wv;  j = i - 131072; }
    else if (i < 196864) { src = bq;  j = i - 196608; }
    else if (i < 197120) { src = bk;  j = i - 196864; }
    else if (i < 197376) { src = bv;  j = i - 197120; }
    else if (i < 213760) { src = Wo;  j = i - 197376; }
    else if (i < 213824) { src = Wob; j = i - 213760; }
    else if (i < 213828) { src = bb;  j = i - 213824; }
    else                 { src = proj; j = i - P_PROJ; }
    params[i] = f ? ((const float*)src)[j] : u2f(((const u16*)src)[j]);
}

// ---------------- hi/lo bf16 split of W (once; gemm staging becomes pure copy) ----------------
__global__ __launch_bounds__(256) void k_cvt_w(const float* __restrict__ params,
                                               u16* __restrict__ Wh, u16* __restrict__ Wl)
{
    int i = blockIdx.x * 256 + threadIdx.x;   // grid = 768 blocks, 196608 exact
    float x = params[P_WF + i];
    u16 h = f2bf(x);
    Wh[i] = h;
    Wl[i] = f2bf(x - u2f(h));
}

// ---------------- degrees ----------------
__global__ __launch_bounds__(256) void k_deg(const int* __restrict__ ei, int* __restrict__ din, int* __restrict__ dout) {
    int e = blockIdx.x * 256 + threadIdx.x;
    if (e >= NE) return;
    atomicAdd(&dout[ei[e]], 1);
    atomicAdd(&din[ei[NE + e]], 1);
}

// ---------------- scan-free CSR offsets ----------------
__global__ __launch_bounds__(256) void k_off(const int* __restrict__ din, int* __restrict__ offn, int* __restrict__ counter) {
    __shared__ int s[256];
    __shared__ int base;
    int tid = threadIdx.x;
    int n = blockIdx.x * 256 + tid;
    int v = (n < NN) ? din[n] : 0;
    s[tid] = v;
    __syncthreads();
    for (int o = 1; o < 256; o <<= 1) {
        int t = (tid >= o) ? s[tid - o] : 0;
        __syncthreads();
        s[tid] += t;
        __syncthreads();
    }
    if (tid == 255) base = atomicAdd(counter, s[255]);
    __syncthreads();
    if (n < NN) offn[n] = base + s[tid] - v;
}

// fill CSR + precompute per-edge conv weight w = rsqrt(din[t]*dout[s])
__global__ __launch_bounds__(256) void k_fill(const int* __restrict__ ei, const int* __restrict__ offn,
                                              int* __restrict__ fill, int* __restrict__ csr,
                                              const int* __restrict__ din, const int* __restrict__ dout,
                                              float* __restrict__ wedge) {
    int e = blockIdx.x * 256 + threadIdx.x;
    if (e >= NE) return;
    int s = ei[e], t = ei[NE + e];
    int pos = offn[t] + atomicAdd(&fill[t], 1);
    csr[pos] = s;
    wedge[pos] = rsqrtf((float)din[t] * (float)dout[s]);
}

// ---------------- fused QKV GEMM + Performer epilogue (register-A, 12-panel loop) ----------------
// Round 25: the 153us was NOT the GEMM loop -- per-block serial path gives
// ~30K cycles/panel vs ~2K of GEMM work. The Performer epilogue's dm loop did
// 1024 scalar ds_read_b32 per thread per Q/K panel (trow[d], projL[m][d]
// element-wise) -> LDS issue pipe (shared per CU) was the bottleneck, which
// also explains why occupancy knobs (r9-r12) never helped. Fix: vectorize the
// dot products to ds_read_b128 (projL stride 65->68 floats = 272B rows, 16B
// aligned; (4r+d)%32 banking -> free 2-way conflicts). Accumulation stays
// element-sequential -> bit-identical. Everything else = round-8 (672.8us).
__global__ __launch_bounds__(256) void k_gemm_feat(
    const void* __restrict__ zv, const float* __restrict__ params, const int* __restrict__ flag,
    const u16* __restrict__ Wh, const u16* __restrict__ Wl,
    u16* __restrict__ V16, float* __restrict__ qp, u16* __restrict__ qp16,
    float* __restrict__ dashK, float* __restrict__ diagK, u32* __restrict__ stab)
{
    __shared__ __align__(16) char AsH[64 * 128];   // A hi chunk plane (128B rows)
    __shared__ __align__(16) char AsL[64 * 128];   // A lo chunk plane
    __shared__ __align__(16) char BsH[64 * 128];   // B hi chunk plane
    __shared__ __align__(16) char BsL[64 * 128];   // B lo chunk plane
    __shared__ __align__(16) float tile[64 * 68];
    __shared__ __align__(16) float projL[30 * 68];
    __shared__ u32 smaxL;

    const int tid = threadIdx.x;
    const int bm = blockIdx.x * 64;
    const int f32 = *flag;
    const int wave = tid >> 6, lane = tid & 63;
    const int wm = wave >> 1, wn = wave & 1;     // 2x2 wave grid, each wave 32x32
    const int sr = tid >> 2;                     // staging row 0..63
    const int sc = (tid & 3) * 16;               // staging col base

    // ---------- load + hi/lo split this thread's 64 A elements, ONCE ----------
    u32 ah[32], al[32];                          // [chunk*8 + j8*4 + p]
    {
        int zrow = bm + sr;
        if (f32) {
            #pragma unroll
            for (int c = 0; c < 4; ++c) {
                float x[16];
                if (zrow < NN) {
                    const float4* zp = (const float4*)((const float*)zv + (size_t)zrow * 256 + c * 64 + sc);
                    #pragma unroll
                    for (int q4 = 0; q4 < 4; ++q4) {
                        float4 v = zp[q4];
                        x[q4 * 4 + 0] = v.x; x[q4 * 4 + 1] = v.y;
                        x[q4 * 4 + 2] = v.z; x[q4 * 4 + 3] = v.w;
                    }
                } else {
                    #pragma unroll
                    for (int j = 0; j < 16; ++j) x[j] = 0.f;
                }
                #pragma unroll
                for (int j8 = 0; j8 < 2; ++j8)
                    #pragma unroll
                    for (int p = 0; p < 4; ++p) {
                        float a = x[j8 * 8 + 2 * p], b2 = x[j8 * 8 + 2 * p + 1];
                        u16 ha = f2bf(a), hb = f2bf(b2);
                        ah[c * 8 + j8 * 4 + p] = (u32)ha | ((u32)hb << 16);
                        u16 la = f2bf(a - u2f(ha)), lb = f2bf(b2 - u2f(hb));
                        al[c * 8 + j8 * 4 + p] = (u32)la | ((u32)lb << 16);
                    }
            }
        } else {
            #pragma unroll
            for (int c = 0; c < 4; ++c) {
                uint4 v0 = make_uint4(0, 0, 0, 0), v1 = v0;
                if (zrow < NN) {
                    const uint4* zp = (const uint4*)((const u16*)zv + (size_t)zrow * 256 + c * 64 + sc);
                    v0 = zp[0]; v1 = zp[1];
                }
                ah[c * 8 + 0] = v0.x; ah[c * 8 + 1] = v0.y; ah[c * 8 + 2] = v0.z; ah[c * 8 + 3] = v0.w;
                ah[c * 8 + 4] = v1.x; ah[c * 8 + 5] = v1.y; ah[c * 8 + 6] = v1.z; ah[c * 8 + 7] = v1.w;
            }
        }
    }
    for (int i2 = tid; i2 < MF * DH; i2 += 256) projL[(i2 >> 6) * 68 + (i2 & 63)] = params[P_PROJ + i2];

    const float* bfv = params + P_BF;
    float scale = DNRM * rsqrtf(params[P_TAU]);
    const int byt0 = sr * 128 + (((sc + 0) * 2) ^ ((sr & 7) << 4));
    const int byt1 = sr * 128 + (((sc + 8) * 2) ^ ((sr & 7) << 4));

    for (int bny = 0; bny < 12; ++bny) {
        const int bn = bny * 64;
        f32x4 acc[2][2] = {};
        #pragma unroll
        for (int k0c = 0; k0c < 4; ++k0c) {
            const int k0 = k0c * 64;
            __syncthreads();   // prev chunk (or prev panel tail) reads done
            // ---- A chunk from registers ----
            *(uint4*)(AsH + byt0) = make_uint4(ah[k0c * 8 + 0], ah[k0c * 8 + 1], ah[k0c * 8 + 2], ah[k0c * 8 + 3]);
            *(uint4*)(AsH + byt1) = make_uint4(ah[k0c * 8 + 4], ah[k0c * 8 + 5], ah[k0c * 8 + 6], ah[k0c * 8 + 7]);
            if (f32) {
                *(uint4*)(AsL + byt0) = make_uint4(al[k0c * 8 + 0], al[k0c * 8 + 1], al[k0c * 8 + 2], al[k0c * 8 + 3]);
                *(uint4*)(AsL + byt1) = make_uint4(al[k0c * 8 + 4], al[k0c * 8 + 5], al[k0c * 8 + 6], al[k0c * 8 + 7]);
            }
            // ---- B chunk (pure copy from preconverted W hi/lo) ----
            {
                const uint4* wh4 = (const uint4*)(Wh + (size_t)(bn + sr) * 256 + k0 + sc);
                *(uint4*)(BsH + byt0) = wh4[0];
                *(uint4*)(BsH + byt1) = wh4[1];
                if (f32) {
                    const uint4* wl4 = (const uint4*)(Wl + (size_t)(bn + sr) * 256 + k0 + sc);
                    *(uint4*)(BsL + byt0) = wl4[0];
                    *(uint4*)(BsL + byt1) = wl4[1];
                }
            }
            __syncthreads();
            // ---- MFMA: 2 k-steps of 32 ----
            #pragma unroll
            for (int kk = 0; kk < 2; ++kk) {
                const int kb = (kk * 32 + ((lane >> 4) * 8)) * 2;
                bf16x8 ahf[2], bhf[2], alf[2], blf[2];
                #pragma unroll
                for (int i = 0; i < 2; ++i) {
                    int ar = 32 * wm + 16 * i + (lane & 15);
                    int ab = ar * 128 + (kb ^ ((ar & 7) << 4));
                    ahf[i] = *(const bf16x8*)(AsH + ab);
                    int br = 32 * wn + 16 * i + (lane & 15);
                    int bb2 = br * 128 + (kb ^ ((br & 7) << 4));
                    bhf[i] = *(const bf16x8*)(BsH + bb2);
                    if (f32) {
                        alf[i] = *(const bf16x8*)(AsL + ab);
                        blf[i] = *(const bf16x8*)(BsL + bb2);
                    }
                }
                #pragma unroll
                for (int i = 0; i < 2; ++i)
                    #pragma unroll
                    for (int nf = 0; nf < 2; ++nf) {
                        acc[i][nf] = __builtin_amdgcn_mfma_f32_16x16x32_bf16(ahf[i], bhf[nf], acc[i][nf], 0, 0, 0);
                        if (f32) {
                            acc[i][nf] = __builtin_amdgcn_mfma_f32_16x16x32_bf16(ahf[i], blf[nf], acc[i][nf], 0, 0, 0);
                            acc[i][nf] = __builtin_amdgcn_mfma_f32_16x16x32_bf16(alf[i], bhf[nf], acc[i][nf], 0, 0, 0);
                        }
                    }
            }
        }
        // ---- epilogue for this panel (tile/projL regions untouched by staging) ----
        if (bny >= 8) {   // V panel: acc -> tile (+bias) -> coalesced bf16 store
            #pragma unroll
            for (int i = 0; i < 2; ++i)
                #pragma unroll
                for (int nf = 0; nf < 2; ++nf) {
                    int col = 32 * wn + 16 * nf + (lane & 15);
                    float bias = bfv[bn + col];
                    #pragma unroll
                    for (int r2 = 0; r2 < 4; ++r2) {
                        int row = 32 * wm + 16 * i + ((lane >> 4) * 4) + r2;
                        tile[row * 68 + col] = acc[i][nf][r2] + bias;
                    }
                }
            __syncthreads();
            for (int i2 = tid; i2 < 4096; i2 += 256) {
                int row = i2 >> 6, col = i2 & 63;
                int nrow = bm + row;
                if (nrow < NN) V16[(size_t)nrow * 256 + (bn - 512) + col] = f2bf(tile[row * 68 + col]);
            }
            continue;
        }

        // Q/K panels: performer features on the 64x64 head tile
        if (tid == 0) smaxL = 0u;
        #pragma unroll
        for (int i = 0; i < 2; ++i)
            #pragma unroll
            for (int nf = 0; nf < 2; ++nf) {
                int col = 32 * wn + 16 * nf + (lane & 15);
                float bias = bfv[bn + col];
                #pragma unroll
                for (int r2 = 0; r2 < 4; ++r2) {
                    int row = 32 * wm + 16 * i + ((lane >> 4) * 4) + r2;
                    tile[row * 68 + col] = (acc[i][nf][r2] + bias) * scale;
                }
            }
        __syncthreads();

        int r = tid >> 2, q = tid & 3;      // 4 lanes cooperate per row; same wave
        int n = bm + r;
        const float* trow = tile + r * 68;
        float dp = 0.f;
        {   // 16 scalar reads -> 4x ds_read_b128; element-sequential adds (bit-identical)
            const float4* t4 = (const float4*)(trow + q * 16);
            #pragma unroll
            for (int d4 = 0; d4 < 4; ++d4) {
                float4 tv = t4[d4];
                dp += tv.x * tv.x; dp += tv.y * tv.y; dp += tv.z * tv.z; dp += tv.w * tv.w;
            }
        }
        dp += __shfl_xor(dp, 1);
        dp += __shfl_xor(dp, 2);
        float diag = dp * 0.5f;

        float dm[8];
        int nm = 0;
        float lmax = -3.0e38f;
        for (int m = q; m < MF; m += 4) {
            float s = 0.f;
            const float4* a4 = (const float4*)trow;
            const float4* b4 = (const float4*)(projL + m * 68);
            #pragma unroll
            for (int d4 = 0; d4 < 16; ++d4) {   // 128 scalar reads -> 32x ds_read_b128
                float4 av = a4[d4], bv = b4[d4];
                s += av.x * bv.x; s += av.y * bv.y; s += av.z * bv.z; s += av.w * bv.w;
            }
            dm[nm++] = s;
            lmax = fmaxf(lmax, s);
        }
        float mx = fmaxf(lmax, __shfl_xor(lmax, 1));
        mx = fmaxf(mx, __shfl_xor(mx, 2));

        if (bny < 4) {   // Q: row-local stab, write qp (fp32) + packed bf16 copy
            int h = bny;
            if (n < NN) {
                float* o = qp + ((size_t)n * NH + h) * MF;
                u16* o16 = qp16 + ((size_t)n * NH + h) * 32;
                nm = 0;
                for (int m = q; m < MF; m += 4) {
                    float v = RATIO * (expf(dm[nm++] - diag - mx) + 1e-6f);
                    o[m] = v;
                    o16[m] = f2bf(v);
                }
                if (q == 0) { o16[30] = 0; o16[31] = 0; }
            }
        } else {          // K: store dash/diag, global per-head max
            int h = bny - 4;
            if (n < NN) {
                float* o = dashK + ((size_t)n * NH + h) * MF;
                nm = 0;
                for (int m = q; m < MF; m += 4) o[m] = dm[nm++];
                if (q == 0) {
                    diagK[(size_t)n * NH + h] = diag;
                    atomicMax(&smaxL, encf(mx));
                }
            }
            __syncthreads();
            if (tid == 0) atomicMax(&stab[h], smaxL);
        }
    }
}

// ---------------- keys pass 2: kp in-place + kpsum + packed bf16 copy ----------------
__global__ __launch_bounds__(256) void k_kp(float* __restrict__ kp, const float* __restrict__ diagK,
                                            const u32* __restrict__ stab, float* __restrict__ kpsum,
                                            u16* __restrict__ kp16)
{
    __shared__ float part[NH * MF];
    __shared__ float stabf[4];
    int tid = threadIdx.x;
    if (tid < NH * MF) part[tid] = 0.f;
    if (tid >= 128 && tid < 132) stabf[tid - 128] = decf(stab[tid - 128]);
    __syncthreads();
    int base = blockIdx.x * 64 * MF;   // 64 rows/block, exact: 1875*64 = 120000
    for (int i = tid; i < 64 * MF; i += 256) {
        int row = blockIdx.x * 64 + i / MF;
        int m = i - (i / MF) * MF;
        int h = row & 3;
        float v = RATIO * (expf(kp[base + i] - diagK[row] - stabf[h]) + 1e-6f);
        kp[base + i] = v;
        kp16[(size_t)row * 32 + m] = f2bf(v);
        atomicAdd(&part[h * MF + m], v);
    }
    if (tid < 64) {
        int row = blockIdx.x * 64 + tid;
        kp16[(size_t)row * 32 + 30] = 0;
        kp16[(size_t)row * 32 + 31] = 0;
    }
    __syncthreads();
    if (tid < NH * MF) atomicAdd(&kpsum[tid], part[tid]);
}

// ---------------- attn_norm[n,h] = qp[n,h,:] . kpsum[h,:] ----------------
__global__ __launch_bounds__(256) void k_an(const float* __restrict__ qp, const float* __restrict__ kpsum,
                                            float* __restrict__ an)
{
    __shared__ float kps[NH * MF];
    int tid = threadIdx.x;
    if (tid < NH * MF) kps[tid] = kpsum[tid];
    __syncthreads();
    int idx = blockIdx.x * 256 + tid;
    if (idx >= NN * NH) return;
    int h = idx & 3;
    const float* q = qp + (size_t)idx * MF;
    float s = 0.f;
    #pragma unroll
    for (int m = 0; m < MF; ++m) s += q[m] * kps[h * MF + m];
    an[idx] = s;
}

// ---------------- kvs via MFMA: kvs[h, km, d] = sum_n kg[n,km] * V[n,h,d] ----------------
#define KVS_CHUNKS 50
#define KVS_NPB (NN / KVS_CHUNKS)    /* 600 nodes per block */
__global__ __launch_bounds__(512) void k_kvs(const float* __restrict__ kp, const void* __restrict__ gum,
                                             const u16* __restrict__ V16, const int* __restrict__ flag,
                                             float* __restrict__ Pkvs, float* __restrict__ Pksum)
{
    __shared__ __align__(16) char kgT[320 * 128];   // 40KB bf16 [320 km][64 n] swizzled
    __shared__ __align__(16) char VT[64 * 128];     //  8KB bf16 [64 d][64 n] swizzled
    __shared__ float kpT[64][31];                    // +1 pad
    __shared__ float egT[64][10];
    const int tid = threadIdx.x;
    const int h = blockIdx.y;
    const int chunk = blockIdx.x;
    const int n0 = chunk * KVS_NPB;
    const int f32 = *flag;
    const int wave = tid >> 6, lane = tid & 63;

    float ksacc[5] = {0.f, 0.f, 0.f, 0.f, 0.f};
    f32x4 acc[10] = {};

    for (int t0 = 0; t0 < KVS_NPB; t0 += 64) {
        __syncthreads();   // prev-tile MFMA reads done
        // ---- stage kp tile (zero-pad past chunk end) ----
        for (int i = tid; i < 64 * MF; i += 512) {
            int n = i / MF, m = i - (i / MF) * MF;
            kpT[n][m] = (t0 + n < KVS_NPB) ? kp[(size_t)(n0 + t0 + n) * (NH * MF) + h * MF + m] : 0.f;
        }
        // ---- stage exp(gumbel) tile ----
        for (int i = tid; i < 64 * KG; i += 512) {
            int n = i / KG, k = i - (i / KG) * KG;
            float e = 0.f;
            if (t0 + n < KVS_NPB) {
                size_t gofs = (size_t)(n0 + t0 + n) * (NH * KG) + h * KG + k;
                float g = f32 ? ((const float*)gum)[gofs] : u2f(((const u16*)gum)[gofs]);
                e = expf(g);
            }
            egT[n][k] = e;
        }
        // ---- stage V^T tile (u16 scatter, swizzled) ----
        for (int i = tid; i < 64 * 16; i += 512) {
            int n = i >> 4, dq = (i & 15) * 4;
            u32 v0 = 0, v1 = 0;
            if (t0 + n < KVS_NPB) {
                uint2 vv = *(const uint2*)(V16 + (size_t)(n0 + t0 + n) * 256 + h * 64 + dq);
                v0 = vv.x; v1 = vv.y;
            }
            #pragma unroll
            for (int j = 0; j < 4; ++j) {
                u16 val = (u16)(((j < 2) ? v0 : v1) >> ((j & 1) * 16));
                int d = dq + j;
                *(u16*)(VT + d * 128 + ((n * 2) ^ ((d & 7) << 4))) = val;
            }
        }
        __syncthreads();
        // ---- build kgT = bf16(kp * eg); accumulate ksum from the rounded values ----
        #pragma unroll
        for (int it = 0; it < 5; ++it) {
            int idx = tid + it * 512;          // 2560 = 320 rows x 8 n-chunks
            int row = idx >> 3, nc = idx & 7;
            u32 w_[4] = {0u, 0u, 0u, 0u};
            if (row < 300) {
                int k = row / MF, m = row - (row / MF) * MF;
                float s = 0.f;
                #pragma unroll
                for (int p = 0; p < 4; ++p) {
                    int na = nc * 8 + 2 * p, nb = na + 1;
                    u16 ha = f2bf(kpT[na][m] * egT[na][k]);
                    u16 hb = f2bf(kpT[nb][m] * egT[nb][k]);
                    w_[p] = (u32)ha | ((u32)hb << 16);
                    s += u2f(ha) + u2f(hb);
                }
                ksacc[it] += s;
            }
            *(uint4*)(kgT + row * 128 + ((nc * 16) ^ ((row & 7) << 4))) = make_uint4(w_[0], w_[1], w_[2], w_[3]);
        }
        __syncthreads();
        // ---- MFMA: wave owns C-tiles ct = wave*10 + i; kt = ct/4 (km), dt = ct%4 (d) ----
        #pragma unroll
        for (int kk = 0; kk < 2; ++kk) {
            const int kb = (kk * 32 + ((lane >> 4) * 8)) * 2;
            #pragma unroll
            for (int i = 0; i < 10; ++i) {
                int ct = wave * 10 + i;
                int kt = ct >> 2, dt = ct & 3;
                int ar = kt * 16 + (lane & 15);
                bf16x8 a = *(const bf16x8*)(kgT + ar * 128 + (kb ^ ((ar & 7) << 4)));
                int br = dt * 16 + (lane & 15);
                bf16x8 b = *(const bf16x8*)(VT + br * 128 + (kb ^ ((br & 7) << 4)));
                acc[i] = __builtin_amdgcn_mfma_f32_16x16x32_bf16(a, b, acc[i], 0, 0, 0);
            }
        }
    }
    // ---- write Pkvs partials: [chunk][h][300][64] ----
    #pragma unroll
    for (int i = 0; i < 10; ++i) {
        int ct = wave * 10 + i;
        int kt = ct >> 2, dt = ct & 3;
        int col = dt * 16 + (lane & 15);
        #pragma unroll
        for (int r = 0; r < 4; ++r) {
            int row = kt * 16 + ((lane >> 4) * 4) + r;
            if (row < 300)
                Pkvs[(((size_t)chunk * NH + h) * 300 + row) * 64 + col] = acc[i][r];
        }
    }
    // ---- ksum partial: reduce across the 8 n-chunk threads of each row ----
    #pragma unroll
    for (int it = 0; it < 5; ++it) {
        float v = ksacc[it];
        v += __shfl_xor(v, 1);
        v += __shfl_xor(v, 2);
        v += __shfl_xor(v, 4);
        int row = (tid + it * 512) >> 3;
        if ((tid & 7) == 0 && row < 300)
            Pksum[chunk * 1200 + h * 300 + row] = v;
    }
}

// ---------------- reduce partials -> kvs, ksum ----------------
__global__ __launch_bounds__(256) void k_reduce(const float* __restrict__ Pkvs, const float* __restrict__ Pksum,
                                                float* __restrict__ kvs, float* __restrict__ ksum)
{
    int i = blockIdx.x * 256 + threadIdx.x;
    if (i < NH * KG * MF * DH) {
        float s = 0.f;
        for (int c = 0; c < KVS_CHUNKS; ++c) s += Pkvs[(size_t)c * (NH * 300 * 64) + i];
        kvs[i] = s;
    } else if (i < NH * KG * MF * DH + NH * KG * MF) {
        int j = i - NH * KG * MF * DH;
        float s = 0.f;
        for (int c = 0; c < KVS_CHUNKS; ++c) s += Pksum[c * 1200 + j];
        ksum[j] = s;
    }
}

// ---------------- per-edge attention weights -> link loss partials ----------------
__global__ __launch_bounds__(256) void k_edge(const int* __restrict__ ei,
                                              const u16* __restrict__ qp16, const u16* __restrict__ kp16,
                                              const float* __restrict__ an,
                                              const int* __restrict__ din, float* __restrict__ lossp)
{
    __shared__ float ls[64];
    int tid = threadIdx.x;
    int eg = tid >> 2, h = tid & 3;
    int e = blockIdx.x * 64 + eg;           // grid = NE/64 exact
    int s = ei[e], t = ei[NE + e];
    const uint4* qv = (const uint4*)(qp16 + ((size_t)t * NH + h) * 32);
    const uint4* kv = (const uint4*)(kp16 + ((size_t)s * NH + h) * 32);
    float num = 0.f;
    #pragma unroll
    for (int c = 0; c < 4; ++c) {
        uint4 a = qv[c], b = kv[c];
        num += u2f((u16)(a.x & 0xFFFF)) * u2f((u16)(b.x & 0xFFFF))
             + u2f((u16)(a.x >> 16))    * u2f((u16)(b.x >> 16))
             + u2f((u16)(a.y & 0xFFFF)) * u2f((u16)(b.y & 0xFFFF))
             + u2f((u16)(a.y >> 16))    * u2f((u16)(b.y >> 16))
             + u2f((u16)(a.z & 0xFFFF)) * u2f((u16)(b.z & 0xFFFF))
             + u2f((u16)(a.z >> 16))    * u2f((u16)(b.z >> 16))
             + u2f((u16)(a.w & 0xFFFF)) * u2f((u16)(b.w & 0xFFFF))
             + u2f((u16)(a.w >> 16))    * u2f((u16)(b.w >> 16));
    }
    float term = logf(num / an[(size_t)t * NH + h]);
    term += __shfl_xor(term, 1);
    term += __shfl_xor(term, 2);
    if (h == 0) ls[eg] = term / (float)din[t];
    __syncthreads();
    if (tid < 64) {
        float v = ls[tid];
        #pragma unroll
        for (int o = 32; o > 0; o >>= 1) v += __shfl_xor(v, o);
        if (tid == 0) atomicAdd(&lossp[blockIdx.x & 1023], v);
    }
}

// ---------------- attention readout: 48 nodes/block (3x16 sub-tiles) ----------------
#define AT_NT 48
__global__ __launch_bounds__(256) void k_attn(
    const float* __restrict__ qp, const float* __restrict__ kvs, const float* __restrict__ ksum,
    u16* __restrict__ zatt)
{
    __shared__ float qpTf[3][NH * 484];       // per 16-node sub-tile: plane h [m][j] stride 16
    __shared__ u32   kvbuf[NH * 964];         // bf16 kvs plane (stride 1928 u16); prologue alias: ksL fp32
    __shared__ float rdenL[3][16 * NH * KG];  // [sub][j][h][k]
    u16*   kvL16 = (u16*)kvbuf;
    float* ksL   = (float*)kvbuf;             // 1200 floats, dead before first kv stage
    int tid = threadIdx.x;
    int n0 = blockIdx.x * AT_NT;              // grid = NN/48 = 625 exact

    for (int i = tid; i < AT_NT * NH * MF; i += 256) {   // qp -> transposed LDS
        int j48 = i / (NH * MF); int r = i - j48 * (NH * MF);
        int h = r / MF; int m = r - h * MF;
        qpTf[j48 >> 4][h * 484 + m * 16 + (j48 & 15)] = qp[(size_t)(n0 + j48) * (NH * MF) + r];
    }
    for (int i = tid; i < NH * KG * MF; i += 256) ksL[i] = ksum[i];
    __syncthreads();
    for (int i = tid; i < AT_NT * NH * KG; i += 256) {   // rden = 1/(qp.ksum)
        int j48 = i / (NH * KG); int r = i - j48 * (NH * KG);
        int h = r / KG;
        int sub = j48 >> 4, j = j48 & 15;
        float s = 0.f;
        #pragma unroll
        for (int m = 0; m < MF; ++m) s += qpTf[sub][h * 484 + m * 16 + j] * ksL[r * MF + m];
        rdenL[sub][j * (NH * KG) + r] = 1.0f / s;
    }

    const int h  = tid >> 6;
    const int jg = (tid >> 4) & 3;
    const int dg = tid & 15;
    float acc[3][4][4] = {};
    for (int k = 0; k < KG; ++k) {
        __syncthreads();   // also protects ksL->kvL16 overlay on first iteration
        for (int i = tid; i < NH * MF * DH; i += 256) {  // stage kvs[:,k,:,:] as bf16
            int hh = i / (MF * DH); int r = i - hh * (MF * DH);
            kvL16[hh * 1928 + r] = f2bf(kvs[((size_t)(hh * 10 + k) * MF) * DH + r]);
        }
        __syncthreads();
        float ps[3][4][4] = {};
        const u16* kb = kvL16 + h * 1928 + dg * 4;
        const float* qb0 = qpTf[0] + h * 484 + jg * 4;
        const float* qb1 = qpTf[1] + h * 484 + jg * 4;
        const float* qb2 = qpTf[2] + h * 484 + jg * 4;
        #pragma unroll
        for (int m = 0; m < MF; ++m) {
            ushort4 bu = *(const ushort4*)(kb + m * 64);
            float4 b = make_float4(u2f(bu.x), u2f(bu.y), u2f(bu.z), u2f(bu.w));
            float4 a0 = *(const float4*)(qb0 + m * 16);
            float4 a1 = *(const float4*)(qb1 + m * 16);
            float4 a2 = *(const float4*)(qb2 + m * 16);
            ps[0][0][0] += a0.x * b.x; ps[0][0][1] += a0.x * b.y; ps[0][0][2] += a0.x * b.z; ps[0][0][3] += a0.x * b.w;
            ps[0][1][0] += a0.y * b.x; ps[0][1][1] += a0.y * b.y; ps[0][1][2] += a0.y * b.z; ps[0][1][3] += a0.y * b.w;
            ps[0][2][0] += a0.z * b.x; ps[0][2][1] += a0.z * b.y; ps[0][2][2] += a0.z * b.z; ps[0][2][3] += a0.z * b.w;
            ps[0][3][0] += a0.w * b.x; ps[0][3][1] += a0.w * b.y; ps[0][3][2] += a0.w * b.z; ps[0][3][3] += a0.w * b.w;
            ps[1][0][0] += a1.x * b.x; ps[1][0][1] += a1.x * b.y; ps[1][0][2] += a1.x * b.z; ps[1][0][3] += a1.x * b.w;
            ps[1][1][0] += a1.y * b.x; ps[1][1][1] += a1.y * b.y; ps[1][1][2] += a1.y * b.z; ps[1][1][3] += a1.y * b.w;
            ps[1][2][0] += a1.z * b.x; ps[1][2][1] += a1.z * b.y; ps[1][2][2] += a1.z * b.z; ps[1][2][3] += a1.z * b.w;
            ps[1][3][0] += a1.w * b.x; ps[1][3][1] += a1.w * b.y; ps[1][3][2] += a1.w * b.z; ps[1][3][3] += a1.w * b.w;
            ps[2][0][0] += a2.x * b.x; ps[2][0][1] += a2.x * b.y; ps[2][0][2] += a2.x * b.z; ps[2][0][3] += a2.x * b.w;
            ps[2][1][0] += a2.y * b.x; ps[2][1][1] += a2.y * b.y; ps[2][1][2] += a2.y * b.z; ps[2][1][3] += a2.y * b.w;
            ps[2][2][0] += a2.z * b.x; ps[2][2][1] += a2.z * b.y; ps[2][2][2] += a2.z * b.z; ps[2][2][3] += a2.z * b.w;
            ps[2][3][0] += a2.w * b.x; ps[2][3][1] += a2.w * b.y; ps[2][3][2] += a2.w * b.z; ps[2][3][3] += a2.w * b.w;
        }
        #pragma unroll
        for (int sub = 0; sub < 3; ++sub)
            #pragma unroll
            for (int j4 = 0; j4 < 4; ++j4) {
                float rd = rdenL[sub][(jg * 4 + j4) * (NH * KG) + h * KG + k];
                #pragma unroll
                for (int d4 = 0; d4 < 4; ++d4) acc[sub][j4][d4] += ps[sub][j4][d4] * rd;
            }
    }
    #pragma unroll
    for (int sub = 0; sub < 3; ++sub)
        #pragma unroll
        for (int j4 = 0; j4 < 4; ++j4) {
            int n = n0 + sub * 16 + jg * 4 + j4;
            #pragma unroll
            for (int d4 = 0; d4 < 4; ++d4)
                zatt[(size_t)n * 256 + h * 64 + dg * 4 + d4] = f2bf(acc[sub][j4][d4] * (1.0f / KG));
        }
}

// ---------------- conv gather: wave-per-node, zero barriers ----------------
__global__ __launch_bounds__(256) void k_gather(
    const u16* __restrict__ zatt, const u16* __restrict__ V16,
    const int* __restrict__ csr, const float* __restrict__ wedge,
    const int* __restrict__ offn, const int* __restrict__ din,
    const float* __restrict__ params, u16* __restrict__ pre)
{
    int tid = threadIdx.x;
    int w = tid >> 6, l = tid & 63;
    int n = blockIdx.x * 4 + w;             // grid = NN/4 = 7500 exact
    float sigb = 1.f / (1.f + expf(-params[P_BBF + (l >> 4)]));   // head of elems l*4..l*4+3
    int dn = din[n], o0 = offn[n];
    float c0 = 0.f, c1 = 0.f, c2 = 0.f, c3 = 0.f;
    for (int t0 = 0; t0 < dn; t0 += 64) {
        int cnt = min(64, dn - t0);
        int myIdx = 0; float myW = 0.f;
        if (l < cnt) { myIdx = csr[o0 + t0 + l]; myW = wedge[o0 + t0 + l]; }
        int j = 0;
        for (; j + 7 < cnt; j += 8) {       // 8 rows in flight (wave-uniform trip count)
            int   s0 = __shfl(myIdx, j),     s1 = __shfl(myIdx, j + 1);
            int   s2 = __shfl(myIdx, j + 2), s3 = __shfl(myIdx, j + 3);
            int   s4 = __shfl(myIdx, j + 4), s5 = __shfl(myIdx, j + 5);
            int   s6 = __shfl(myIdx, j + 6), s7 = __shfl(myIdx, j + 7);
            float w0 = __shfl(myW, j),     w1 = __shfl(myW, j + 1);
            float w2 = __shfl(myW, j + 2), w3 = __shfl(myW, j + 3);
            float w4 = __shfl(myW, j + 4), w5 = __shfl(myW, j + 5);
            float w6 = __shfl(myW, j + 6), w7 = __shfl(myW, j + 7);
            uint2 a0 = *(const uint2*)(V16 + (size_t)s0 * 256 + l * 4);
            uint2 a1 = *(const uint2*)(V16 + (size_t)s1 * 256 + l * 4);
            uint2 a2 = *(const uint2*)(V16 + (size_t)s2 * 256 + l * 4);
            uint2 a3 = *(const uint2*)(V16 + (size_t)s3 * 256 + l * 4);
            uint2 a4 = *(const uint2*)(V16 + (size_t)s4 * 256 + l * 4);
            uint2 a5 = *(const uint2*)(V16 + (size_t)s5 * 256 + l * 4);
            uint2 a6 = *(const uint2*)(V16 + (size_t)s6 * 256 + l * 4);
            uint2 a7 = *(const uint2*)(V16 + (size_t)s7 * 256 + l * 4);
            c0 += w0 * u2f((u16)(a0.x & 0xFFFF)) + w1 * u2f((u16)(a1.x & 0xFFFF))
                + w2 * u2f((u16)(a2.x & 0xFFFF)) + w3 * u2f((u16)(a3.x & 0xFFFF))
                + w4 * u2f((u16)(a4.x & 0xFFFF)) + w5 * u2f((u16)(a5.x & 0xFFFF))
                + w6 * u2f((u16)(a6.x & 0xFFFF)) + w7 * u2f((u16)(a7.x & 0xFFFF));
            c1 += w0 * u2f((u16)(a0.x >> 16)) + w1 * u2f((u16)(a1.x >> 16))
                + w2 * u2f((u16)(a2.x >> 16)) + w3 * u2f((u16)(a3.x >> 16))
                + w4 * u2f((u16)(a4.x >> 16)) + w5 * u2f((u16)(a5.x >> 16))
                + w6 * u2f((u16)(a6.x >> 16)) + w7 * u2f((u16)(a7.x >> 16));
            c2 += w0 * u2f((u16)(a0.y & 0xFFFF)) + w1 * u2f((u16)(a1.y & 0xFFFF))
                + w2 * u2f((u16)(a2.y & 0xFFFF)) + w3 * u2f((u16)(a3.y & 0xFFFF))
                + w4 * u2f((u16)(a4.y & 0xFFFF)) + w5 * u2f((u16)(a5.y & 0xFFFF))
                + w6 * u2f((u16)(a6.y & 0xFFFF)) + w7 * u2f((u16)(a7.y & 0xFFFF));
            c3 += w0 * u2f((u16)(a0.y >> 16)) + w1 * u2f((u16)(a1.y >> 16))
                + w2 * u2f((u16)(a2.y >> 16)) + w3 * u2f((u16)(a3.y >> 16))
                + w4 * u2f((u16)(a4.y >> 16)) + w5 * u2f((u16)(a5.y >> 16))
                + w6 * u2f((u16)(a6.y >> 16)) + w7 * u2f((u16)(a7.y >> 16));
        }
        for (; j < cnt; ++j) {
            int   s0 = __shfl(myIdx, j);
            float w0 = __shfl(myW, j);
            uint2 a0 = *(const uint2*)(V16 + (size_t)s0 * 256 + l * 4);
            c0 += w0 * u2f((u16)(a0.x & 0xFFFF));
            c1 += w0 * u2f((u16)(a0.x >> 16));
            c2 += w0 * u2f((u16)(a0.y & 0xFFFF));
            c3 += w0 * u2f((u16)(a0.y >> 16));
        }
    }
    uint2 za = *(const uint2*)(zatt + (size_t)n * 256 + l * 4);
    float e0 = u2f((u16)(za.x & 0xFFFF)) + sigb * c0;
    float e1 = u2f((u16)(za.x >> 16))    + sigb * c1;
    float e2 = u2f((u16)(za.y & 0xFFFF)) + sigb * c2;
    float e3 = u2f((u16)(za.y >> 16))    + sigb * c3;
    uint2 r;
    r.x = (u32)f2bf(e0) | ((u32)f2bf(e1) << 16);
    r.y = (u32)f2bf(e2) | ((u32)f2bf(e3) << 16);
    *(uint2*)(pre + (size_t)n * 256 + l * 4) = r;
}

// ---------------- out = pre(bf16) x Wo^T via MFMA (Wo hi/lo split on the fly) ----------------
__global__ __launch_bounds__(256) void k_out(
    const u16* __restrict__ pre, const float* __restrict__ params, float* __restrict__ out)
{
    __shared__ __align__(16) char smemc[24576];   // As(8KB) | BsH(8KB) | BsL(8KB)
    char* As  = smemc;
    char* BsH = smemc + 8192;
    char* BsL = smemc + 16384;
    const int tid = threadIdx.x;
    const int bm = blockIdx.x * 64;
    const int wave = tid >> 6, lane = tid & 63;
    const int wm = wave >> 1, wn = wave & 1;
    const int sr = tid >> 2;
    const int sc = (tid & 3) * 16;

    f32x4 acc[2][2] = {};

    for (int k0 = 0; k0 < 256; k0 += 64) {
        __syncthreads();
        int byt0 = sr * 128 + (((sc + 0) * 2) ^ ((sr & 7) << 4));
        int byt1 = sr * 128 + (((sc + 8) * 2) ^ ((sr & 7) << 4));
        {   // ---- stage A: pre rows (bf16 copy) ----
            int row = bm + sr;
            uint4 v0 = make_uint4(0, 0, 0, 0), v1 = v0;
            if (row < NN) {
                const uint4* p = (const uint4*)(pre + (size_t)row * 256 + k0 + sc);
                v0 = p[0]; v1 = p[1];
            }
            *(uint4*)(As + byt0) = v0;
            *(uint4*)(As + byt1) = v1;
        }
        {   // ---- stage B: Wo fp32 -> hi/lo bf16 planes ----
            float x[16];
            const float4* wr = (const float4*)(params + P_WOF + (size_t)sr * 256 + k0 + sc);
            #pragma unroll
            for (int q4 = 0; q4 < 4; ++q4) {
                float4 v = wr[q4];
                x[q4 * 4 + 0] = v.x; x[q4 * 4 + 1] = v.y;
                x[q4 * 4 + 2] = v.z; x[q4 * 4 + 3] = v.w;
            }
            #pragma unroll
            for (int j8 = 0; j8 < 2; ++j8) {
                u32 hw[4], lw[4];
                #pragma unroll
                for (int p = 0; p < 4; ++p) {
                    float a = x[j8 * 8 + 2 * p], b2 = x[j8 * 8 + 2 * p + 1];
                    u16 ha = f2bf(a), hb = f2bf(b2);
                    hw[p] = (u32)ha | ((u32)hb << 16);
                    u16 la = f2bf(a - u2f(ha)), lb = f2bf(b2 - u2f(hb));
                    lw[p] = (u32)la | ((u32)lb << 16);
                }
                int byt = sr * 128 + (((sc + j8 * 8) * 2) ^ ((sr & 7) << 4));
                *(uint4*)(BsH + byt) = make_uint4(hw[0], hw[1], hw[2], hw[3]);
                *(uint4*)(BsL + byt) = make_uint4(lw[0], lw[1], lw[2], lw[3]);
            }
        }
        __syncthreads();
        #pragma unroll
        for (int kk = 0; kk < 2; ++kk) {
            const int kb = (kk * 32 + ((lane >> 4) * 8)) * 2;
            bf16x8 a[2], bh[2], bl[2];
            #pragma unroll
            for (int i = 0; i < 2; ++i) {
                int ar = 32 * wm + 16 * i + (lane & 15);
                int ab = ar * 128 + (kb ^ ((ar & 7) << 4));
                a[i] = *(const bf16x8*)(As + ab);
                int br = 32 * wn + 16 * i + (lane & 15);
                int bb2 = br * 128 + (kb ^ ((br & 7) << 4));
                bh[i] = *(const bf16x8*)(BsH + bb2);
                bl[i] = *(const bf16x8*)(BsL + bb2);
            }
            #pragma unroll
            for (int i = 0; i < 2; ++i)
                #pragma unroll
                for (int nf = 0; nf < 2; ++nf) {
                    acc[i][nf] = __builtin_amdgcn_mfma_f32_16x16x32_bf16(a[i], bh[nf], acc[i][nf], 0, 0, 0);
                    acc[i][nf] = __builtin_amdgcn_mfma_f32_16x16x32_bf16(a[i], bl[nf], acc[i][nf], 0, 0, 0);
                }
        }
    }
    #pragma unroll
    for (int i = 0; i < 2; ++i)
        #pragma unroll
        for (int nf = 0; nf < 2; ++nf) {
            int col = 32 * wn + 16 * nf + (lane & 15);
            float bias = params[P_WOBF + col];
            #pragma unroll
            for (int r2 = 0; r2 < 4; ++r2) {
                int row = bm + 32 * wm + 16 * i + ((lane >> 4) * 4) + r2;
                if (row < NN) out[(size_t)row * 64 + col] = acc[i][nf][r2] + bias;
            }
        }
}

// ---------------- loss finalize ----------------
__global__ __launch_bounds__(256) void k_loss(const float* __restrict__ lossp, float* __restrict__ out) {
    __shared__ float s[256];
    int tid = threadIdx.x;
    float v = 0.f;
    for (int i = tid; i < 1024; i += 256) v += lossp[i];
    s[tid] = v;
    __syncthreads();
    for (int o = 128; o > 0; o >>= 1) {
        if (tid < o) s[tid] += s[tid + o];
        __syncthreads();
    }
    if (tid == 0) out[(size_t)NN * 64] = s[0] / (float)(NE * NH);   // fp32 output
}

extern "C" void kernel_launch(void* const* d_in, const int* in_sizes, int n_in,
                              void* d_out, int out_size, void* d_ws, size_t ws_size,
                              hipStream_t stream)
{
    const void* z    = d_in[0];
    const int*  ei   = (const int*)d_in[1];
    const void* taup = d_in[2];
    const void* gum  = d_in[3];
    const void* proj = d_in[4];
    const void* Wq   = d_in[5];
    const void* bq   = d_in[6];
    const void* Wk   = d_in[7];
    const void* bk   = d_in[8];
    const void* Wv   = d_in[9];
    const void* bv   = d_in[10];
    const void* Wo   = d_in[11];
    const void* Wob  = d_in[12];
    const void* bb   = d_in[13];
    float* out = (float*)d_out;

    // ---- workspace carve-up (fp32 units), total ~67 MB ----
    u16*   V16    = (u16*)d_ws;                    //  7,680,000 u16 : [N,256] bf16 V
    float* qpb    = (float*)d_ws + 3840000;        //  3,600,000 : [N,H,M]
    float* kpb    = qpb + (size_t)NN * NH * MF;    //  3,600,000 : dashK then kp in-place
    float* diagK  = kpb + (size_t)NN * NH * MF;    //    120,000
    float* anb    = diagK + (size_t)NN * NH;       //    120,000
    u16*   zatt   = (u16*)kpb;                     //  reuses kpb+diagK+anb (dead after k_edge)
    int*   csr    = (int*)(anb + (size_t)NN * NH); //    480,000
    int*   offn   = csr + NE;                      //     30,000
    float* params = (float*)(offn + NN);           //    215,749 (+pad to 215,752)
    // ---- zeroed accumulator region ----
    float* kvs    = params + 215752;               //     76,800 : [H,K,M,D]
    float* ksum   = kvs + NH * KG * MF * DH;       //      1,200 : [H,K,M]
    float* kpsum  = ksum + NH * KG * MF;           //        120 : [H,M]
    int*   din    = (int*)(kpsum + NH * MF);       //     30,000
    int*   doutd  = din + NN;                      //     30,000
    int*   fill   = doutd + NN;                    //     30,000
    int*   counter = fill + NN;                    //          4
    u32*   stab   = (u32*)(counter + 4);           //          4
    float* lossp  = (float*)(stab + 4);            //      1,024
    int*   flag   = (int*)(lossp + 1024);          //          4
    float* wedge  = (float*)(flag + 4);            //    480,000 (not zeroed; fully written)
    u16*   qp16   = (u16*)(wedge + NE);            //  3,840,000 u16 : [N,H,32] bf16 qp
    u16*   kp16   = qp16 + (size_t)NN * NH * 32;   //  3,840,000 u16 : [N,H,32] bf16 kp
    // kvs partials overlay qp16+kp16 (15.36 MB, exact fit: 50*4*300*64 floats);
    // alive only between k_kvs and k_reduce, after qp16/kp16's last reader (k_edge).
    float* Pkvs   = (float*)qp16;
    float* Pksum  = (float*)(kp16 + (size_t)NN * NH * 32);   //  60,000 floats (new tail)
    // W hi/lo bf16 planes overlay kp16 (dead until k_kp writes it, after k_gemm_feat)
    u16*   Whb    = kp16;                          //    196,608 u16 : [768][256] W hi
    u16*   Wlb    = kp16 + 196608;                 //    196,608 u16 : [768][256] W lo
    // pre[N,256] bf16 overlays qp16+kp16 (7,680,000 u16 exactly); alive only
    // between k_gather and k_out, after Pkvs's last reader (k_reduce).
    u16*   pre    = qp16;
    size_t zero_bytes = (size_t)((char*)(flag + 4) - (char*)kvs);

    hipMemsetAsync(kvs, 0, zero_bytes, stream);

    k_detect<<<dim3(1), dim3(64), 0, stream>>>((const u16*)z, flag);
    k_cvt_params<<<dim3((P_TOTAL + 255) / 256), dim3(256), 0, stream>>>(
        Wq, Wk, Wv, bq, bk, bv, Wo, Wob, bb, proj, taup, params, flag);
    k_cvt_w<<<dim3(768), dim3(256), 0, stream>>>(params, Whb, Wlb);

    k_deg <<<dim3((NE + 255) / 256), dim3(256), 0, stream>>>(ei, din, doutd);
    k_off <<<dim3((NN + 255) / 256), dim3(256), 0, stream>>>(din, offn, counter);
    k_fill<<<dim3((NE + 255) / 256), dim3(256), 0, stream>>>(ei, offn, fill, csr, din, doutd, wedge);
    k_gemm_feat<<<dim3((NN + 63) / 64), dim3(256), 0, stream>>>(
        z, params, flag, Whb, Wlb, V16, qpb, qp16, kpb, diagK, stab);
    k_kp  <<<dim3(NN * NH / 64), dim3(256), 0, stream>>>(kpb, diagK, stab, kpsum, kp16);
    k_an  <<<dim3((NN * NH + 255) / 256), dim3(256), 0, stream>>>(qpb, kpsum, anb);
    k_edge<<<dim3(NE / 64), dim3(256), 0, stream>>>(ei, qp16, kp16, anb, din, lossp);
    // qp16/kp16 dead from here; Pkvs overlays them (stream-ordered)
    k_kvs <<<dim3(KVS_CHUNKS, NH), dim3(512), 0, stream>>>(kpb, gum, V16, flag, Pkvs, Pksum);
    k_reduce<<<dim3((NH * KG * MF * DH + NH * KG * MF + 255) / 256), dim3(256), 0, stream>>>(
        Pkvs, Pksum, kvs, ksum);
    // zatt overwrites kpb/diagK/anb from here on (stream-ordered after their last readers)
    k_attn<<<dim3(NN / AT_NT), dim3(256), 0, stream>>>(qpb, kvs, ksum, zatt);
    // pre overlays qp16/kp16 (Pkvs dead after k_reduce)
    k_gather<<<dim3(NN / 4), dim3(256), 0, stream>>>(zatt, V16, csr, wedge, offn, din, params, pre);
    k_out<<<dim3((NN + 63) / 64), dim3(256), 0, stream>>>(pre, params, out);
    k_loss<<<dim3(1), dim3(256), 0, stream>>>(lossp, out);
}

// Round 15
// 675.681 us; speedup vs baseline: 1.0962x; 1.0962x over previous
//
#include <hip/hip_runtime.h>
#include <hip/hip_bf16.h>

#define NN 30000
#define NE 480000
#define NH 4
#define DH 64
#define MF 30
#define KG 10
#define RATIO 0.18257418583505536f   /* 1/sqrt(30) */
#define DNRM  0.35355339059327373f   /* 64^-0.25  */

// fp32 params block layout (element offsets)
#define P_WF    0        /* [768][256] Wq|Wk|Wv rows */
#define P_BF    196608   /* [768] bq|bk|bv */
#define P_WOF   197376   /* [64][256] Wo */
#define P_WOBF  213760   /* [64] Wo bias */
#define P_BBF   213824   /* [4] rb bias b */
#define P_PROJ  213828   /* [30][64] proj */
#define P_TAU   215748   /* scalar */
#define P_TOTAL 215749

typedef unsigned short u16;
typedef unsigned int   u32;
typedef __attribute__((ext_vector_type(8))) short bf16x8;
typedef __attribute__((ext_vector_type(4))) float f32x4;

__device__ __forceinline__ float u2f(u16 u) { return __uint_as_float(((u32)u) << 16); }
__device__ __forceinline__ u16  f2bf(float f) {  // round-to-nearest-even bf16
    u32 x = __float_as_uint(f);
    return (u16)((x + 0x7FFFu + ((x >> 16) & 1u)) >> 16);
}
// order-preserving float->uint encoding for atomicMax over signed floats
__device__ __forceinline__ u32  encf(float f) { u32 u = __float_as_uint(f); return (u & 0x80000000u) ? ~u : (u | 0x80000000u); }
__device__ __forceinline__ float decf(u32 u)  { return (u & 0x80000000u) ? __uint_as_float(u & 0x7FFFFFFFu) : __uint_as_float(~u); }

// ---------------- dtype detection (fp32 vs bf16 input tensors) ----------------
__global__ void k_detect(const u16* __restrict__ z, int* __restrict__ flag) {
    if (threadIdx.x == 0 && blockIdx.x == 0) {
        int bad = 0;
        for (int i = 0; i < 256; i += 2) {
            u16 u = z[i];
            int e = (u >> 7) & 0xFF;
            if (u != 0 && !(e >= 100 && e <= 140)) bad++;
        }
        *flag = (bad > 16) ? 1 : 0;   // 1 = inputs are fp32
    }
}

// ---------------- stage all small params to fp32 ----------------
__global__ __launch_bounds__(256) void k_cvt_params(
    const void* Wq, const void* Wk, const void* Wv,
    const void* bq, const void* bk, const void* bv,
    const void* Wo, const void* Wob, const void* bb, const void* proj,
    const void* taup, float* __restrict__ params, const int* __restrict__ flag)
{
    int i = blockIdx.x * 256 + threadIdx.x;
    if (i >= P_TOTAL) return;
    int f = *flag;
    if (i == P_TAU) {
        float v = f ? ((const float*)taup)[0] : u2f(((const u16*)taup)[0]);
        if (!(v > 1e-6f && v < 1e6f)) {
            float ff = ((const float*)taup)[0];
            v = (ff > 1e-6f && ff < 1e6f) ? ff : 0.25f;
        }
        params[i] = v;
        return;
    }
    const void* src; int j;
    if      (i < 65536)  { src = Wq;  j = i; }
    else if (i < 131072) { src = Wk;  j = i - 65536; }
    else if (i < 196608) { src = Wv;  j = i - 131072; }
    else if (i < 196864) { src = bq;  j = i - 196608; }
    else if (i < 197120) { src = bk;  j = i - 196864; }
    else if (i < 197376) { src = bv;  j = i - 197120; }
    else if (i < 213760) { src = Wo;  j = i - 197376; }
    else if (i < 213824) { src = Wob; j = i - 213760; }
    else if (i < 213828) { src = bb;  j = i - 213824; }
    else                 { src = proj; j = i - P_PROJ; }
    params[i] = f ? ((const float*)src)[j] : u2f(((const u16*)src)[j]);
}

// ---------------- hi/lo bf16 split of W (once; gemm staging becomes pure copy) ----------------
__global__ __launch_bounds__(256) void k_cvt_w(const float* __restrict__ params,
                                               u16* __restrict__ Wh, u16* __restrict__ Wl)
{
    int i = blockIdx.x * 256 + threadIdx.x;   // grid = 768 blocks, 196608 exact
    float x = params[P_WF + i];
    u16 h = f2bf(x);
    Wh[i] = h;
    Wl[i] = f2bf(x - u2f(h));
}

// ---------------- degrees ----------------
__global__ __launch_bounds__(256) void k_deg(const int* __restrict__ ei, int* __restrict__ din, int* __restrict__ dout) {
    int e = blockIdx.x * 256 + threadIdx.x;
    if (e >= NE) return;
    atomicAdd(&dout[ei[e]], 1);
    atomicAdd(&din[ei[NE + e]], 1);
}

// ---------------- scan-free CSR offsets ----------------
__global__ __launch_bounds__(256) void k_off(const int* __restrict__ din, int* __restrict__ offn, int* __restrict__ counter) {
    __shared__ int s[256];
    __shared__ int base;
    int tid = threadIdx.x;
    int n = blockIdx.x * 256 + tid;
    int v = (n < NN) ? din[n] : 0;
    s[tid] = v;
    __syncthreads();
    for (int o = 1; o < 256; o <<= 1) {
        int t = (tid >= o) ? s[tid - o] : 0;
        __syncthreads();
        s[tid] += t;
        __syncthreads();
    }
    if (tid == 255) base = atomicAdd(counter, s[255]);
    __syncthreads();
    if (n < NN) offn[n] = base + s[tid] - v;
}

// fill CSR + precompute per-edge conv weight w = rsqrt(din[t]*dout[s])
__global__ __launch_bounds__(256) void k_fill(const int* __restrict__ ei, const int* __restrict__ offn,
                                              int* __restrict__ fill, int* __restrict__ csr,
                                              const int* __restrict__ din, const int* __restrict__ dout,
                                              float* __restrict__ wedge) {
    int e = blockIdx.x * 256 + threadIdx.x;
    if (e >= NE) return;
    int s = ei[e], t = ei[NE + e];
    int pos = offn[t] + atomicAdd(&fill[t], 1);
    csr[pos] = s;
    wedge[pos] = rsqrtf((float)din[t] * (float)dout[s]);
}

// ---------------- fused QKV GEMM + Performer epilogue (register-A, 12-panel loop) ----------------
// FINAL: best-measured configuration (676.8us r8 / 672.8us r13). A hi/lo split
// in registers (64 u32/thread, statically indexed); per-chunk A LDS plane (8KB,
// 128B-row XOR-swizzled) refilled from regs per (panel,chunk). LDS ~57KB,
// plain launch_bounds (124 VGPR, no spill). Seven attempted restructurings
// (r9-r12, r14: y-split, tile overlay, 2-plane, dtype-specialization, epilogue
// vectorization) all regressed or were neutral -- this operating point is a
// sharp local optimum (occupancy ~21% invariant under resource knobs).
__global__ __launch_bounds__(256) void k_gemm_feat(
    const void* __restrict__ zv, const float* __restrict__ params, const int* __restrict__ flag,
    const u16* __restrict__ Wh, const u16* __restrict__ Wl,
    u16* __restrict__ V16, float* __restrict__ qp, u16* __restrict__ qp16,
    float* __restrict__ dashK, float* __restrict__ diagK, u32* __restrict__ stab)
{
    __shared__ __align__(16) char AsH[64 * 128];   // A hi chunk plane (128B rows)
    __shared__ __align__(16) char AsL[64 * 128];   // A lo chunk plane
    __shared__ __align__(16) char BsH[64 * 128];   // B hi chunk plane
    __shared__ __align__(16) char BsL[64 * 128];   // B lo chunk plane
    __shared__ float tile[64 * 68];
    __shared__ float projL[30 * 65];
    __shared__ u32 smaxL;

    const int tid = threadIdx.x;
    const int bm = blockIdx.x * 64;
    const int f32 = *flag;
    const int wave = tid >> 6, lane = tid & 63;
    const int wm = wave >> 1, wn = wave & 1;     // 2x2 wave grid, each wave 32x32
    const int sr = tid >> 2;                     // staging row 0..63
    const int sc = (tid & 3) * 16;               // staging col base

    // ---------- load + hi/lo split this thread's 64 A elements, ONCE ----------
    u32 ah[32], al[32];                          // [chunk*8 + j8*4 + p]
    {
        int zrow = bm + sr;
        if (f32) {
            #pragma unroll
            for (int c = 0; c < 4; ++c) {
                float x[16];
                if (zrow < NN) {
                    const float4* zp = (const float4*)((const float*)zv + (size_t)zrow * 256 + c * 64 + sc);
                    #pragma unroll
                    for (int q4 = 0; q4 < 4; ++q4) {
                        float4 v = zp[q4];
                        x[q4 * 4 + 0] = v.x; x[q4 * 4 + 1] = v.y;
                        x[q4 * 4 + 2] = v.z; x[q4 * 4 + 3] = v.w;
                    }
                } else {
                    #pragma unroll
                    for (int j = 0; j < 16; ++j) x[j] = 0.f;
                }
                #pragma unroll
                for (int j8 = 0; j8 < 2; ++j8)
                    #pragma unroll
                    for (int p = 0; p < 4; ++p) {
                        float a = x[j8 * 8 + 2 * p], b2 = x[j8 * 8 + 2 * p + 1];
                        u16 ha = f2bf(a), hb = f2bf(b2);
                        ah[c * 8 + j8 * 4 + p] = (u32)ha | ((u32)hb << 16);
                        u16 la = f2bf(a - u2f(ha)), lb = f2bf(b2 - u2f(hb));
                        al[c * 8 + j8 * 4 + p] = (u32)la | ((u32)lb << 16);
                    }
            }
        } else {
            #pragma unroll
            for (int c = 0; c < 4; ++c) {
                uint4 v0 = make_uint4(0, 0, 0, 0), v1 = v0;
                if (zrow < NN) {
                    const uint4* zp = (const uint4*)((const u16*)zv + (size_t)zrow * 256 + c * 64 + sc);
                    v0 = zp[0]; v1 = zp[1];
                }
                ah[c * 8 + 0] = v0.x; ah[c * 8 + 1] = v0.y; ah[c * 8 + 2] = v0.z; ah[c * 8 + 3] = v0.w;
                ah[c * 8 + 4] = v1.x; ah[c * 8 + 5] = v1.y; ah[c * 8 + 6] = v1.z; ah[c * 8 + 7] = v1.w;
            }
        }
    }
    for (int i2 = tid; i2 < MF * DH; i2 += 256) projL[(i2 >> 6) * 65 + (i2 & 63)] = params[P_PROJ + i2];

    const float* bfv = params + P_BF;
    float scale = DNRM * rsqrtf(params[P_TAU]);
    const int byt0 = sr * 128 + (((sc + 0) * 2) ^ ((sr & 7) << 4));
    const int byt1 = sr * 128 + (((sc + 8) * 2) ^ ((sr & 7) << 4));

    for (int bny = 0; bny < 12; ++bny) {
        const int bn = bny * 64;
        f32x4 acc[2][2] = {};
        #pragma unroll
        for (int k0c = 0; k0c < 4; ++k0c) {
            const int k0 = k0c * 64;
            __syncthreads();   // prev chunk (or prev panel tail) reads done
            // ---- A chunk from registers ----
            *(uint4*)(AsH + byt0) = make_uint4(ah[k0c * 8 + 0], ah[k0c * 8 + 1], ah[k0c * 8 + 2], ah[k0c * 8 + 3]);
            *(uint4*)(AsH + byt1) = make_uint4(ah[k0c * 8 + 4], ah[k0c * 8 + 5], ah[k0c * 8 + 6], ah[k0c * 8 + 7]);
            if (f32) {
                *(uint4*)(AsL + byt0) = make_uint4(al[k0c * 8 + 0], al[k0c * 8 + 1], al[k0c * 8 + 2], al[k0c * 8 + 3]);
                *(uint4*)(AsL + byt1) = make_uint4(al[k0c * 8 + 4], al[k0c * 8 + 5], al[k0c * 8 + 6], al[k0c * 8 + 7]);
            }
            // ---- B chunk (pure copy from preconverted W hi/lo) ----
            {
                const uint4* wh4 = (const uint4*)(Wh + (size_t)(bn + sr) * 256 + k0 + sc);
                *(uint4*)(BsH + byt0) = wh4[0];
                *(uint4*)(BsH + byt1) = wh4[1];
                if (f32) {
                    const uint4* wl4 = (const uint4*)(Wl + (size_t)(bn + sr) * 256 + k0 + sc);
                    *(uint4*)(BsL + byt0) = wl4[0];
                    *(uint4*)(BsL + byt1) = wl4[1];
                }
            }
            __syncthreads();
            // ---- MFMA: 2 k-steps of 32 ----
            #pragma unroll
            for (int kk = 0; kk < 2; ++kk) {
                const int kb = (kk * 32 + ((lane >> 4) * 8)) * 2;
                bf16x8 ahf[2], bhf[2], alf[2], blf[2];
                #pragma unroll
                for (int i = 0; i < 2; ++i) {
                    int ar = 32 * wm + 16 * i + (lane & 15);
                    int ab = ar * 128 + (kb ^ ((ar & 7) << 4));
                    ahf[i] = *(const bf16x8*)(AsH + ab);
                    int br = 32 * wn + 16 * i + (lane & 15);
                    int bb2 = br * 128 + (kb ^ ((br & 7) << 4));
                    bhf[i] = *(const bf16x8*)(BsH + bb2);
                    if (f32) {
                        alf[i] = *(const bf16x8*)(AsL + ab);
                        blf[i] = *(const bf16x8*)(BsL + bb2);
                    }
                }
                #pragma unroll
                for (int i = 0; i < 2; ++i)
                    #pragma unroll
                    for (int nf = 0; nf < 2; ++nf) {
                        acc[i][nf] = __builtin_amdgcn_mfma_f32_16x16x32_bf16(ahf[i], bhf[nf], acc[i][nf], 0, 0, 0);
                        if (f32) {
                            acc[i][nf] = __builtin_amdgcn_mfma_f32_16x16x32_bf16(ahf[i], blf[nf], acc[i][nf], 0, 0, 0);
                            acc[i][nf] = __builtin_amdgcn_mfma_f32_16x16x32_bf16(alf[i], bhf[nf], acc[i][nf], 0, 0, 0);
                        }
                    }
            }
        }
        // ---- epilogue for this panel (tile/projL regions untouched by staging) ----
        if (bny >= 8) {   // V panel: acc -> tile (+bias) -> coalesced bf16 store
            #pragma unroll
            for (int i = 0; i < 2; ++i)
                #pragma unroll
                for (int nf = 0; nf < 2; ++nf) {
                    int col = 32 * wn + 16 * nf + (lane & 15);
                    float bias = bfv[bn + col];
                    #pragma unroll
                    for (int r2 = 0; r2 < 4; ++r2) {
                        int row = 32 * wm + 16 * i + ((lane >> 4) * 4) + r2;
                        tile[row * 68 + col] = acc[i][nf][r2] + bias;
                    }
                }
            __syncthreads();
            for (int i2 = tid; i2 < 4096; i2 += 256) {
                int row = i2 >> 6, col = i2 & 63;
                int nrow = bm + row;
                if (nrow < NN) V16[(size_t)nrow * 256 + (bn - 512) + col] = f2bf(tile[row * 68 + col]);
            }
            continue;
        }

        // Q/K panels: performer features on the 64x64 head tile
        if (tid == 0) smaxL = 0u;
        #pragma unroll
        for (int i = 0; i < 2; ++i)
            #pragma unroll
            for (int nf = 0; nf < 2; ++nf) {
                int col = 32 * wn + 16 * nf + (lane & 15);
                float bias = bfv[bn + col];
                #pragma unroll
                for (int r2 = 0; r2 < 4; ++r2) {
                    int row = 32 * wm + 16 * i + ((lane >> 4) * 4) + r2;
                    tile[row * 68 + col] = (acc[i][nf][r2] + bias) * scale;
                }
            }
        __syncthreads();

        int r = tid >> 2, q = tid & 3;      // 4 lanes cooperate per row; same wave
        int n = bm + r;
        const float* trow = tile + r * 68;
        float dp = 0.f;
        #pragma unroll
        for (int d = q * 16; d < q * 16 + 16; ++d) dp += trow[d] * trow[d];
        dp += __shfl_xor(dp, 1);
        dp += __shfl_xor(dp, 2);
        float diag = dp * 0.5f;

        float dm[8];
        int nm = 0;
        float lmax = -3.0e38f;
        for (int m = q; m < MF; m += 4) {
            float s = 0.f;
            #pragma unroll
            for (int d = 0; d < DH; ++d) s += trow[d] * projL[m * 65 + d];
            dm[nm++] = s;
            lmax = fmaxf(lmax, s);
        }
        float mx = fmaxf(lmax, __shfl_xor(lmax, 1));
        mx = fmaxf(mx, __shfl_xor(mx, 2));

        if (bny < 4) {   // Q: row-local stab, write qp (fp32) + packed bf16 copy
            int h = bny;
            if (n < NN) {
                float* o = qp + ((size_t)n * NH + h) * MF;
                u16* o16 = qp16 + ((size_t)n * NH + h) * 32;
                nm = 0;
                for (int m = q; m < MF; m += 4) {
                    float v = RATIO * (expf(dm[nm++] - diag - mx) + 1e-6f);
                    o[m] = v;
                    o16[m] = f2bf(v);
                }
                if (q == 0) { o16[30] = 0; o16[31] = 0; }
            }
        } else {          // K: store dash/diag, global per-head max
            int h = bny - 4;
            if (n < NN) {
                float* o = dashK + ((size_t)n * NH + h) * MF;
                nm = 0;
                for (int m = q; m < MF; m += 4) o[m] = dm[nm++];
                if (q == 0) {
                    diagK[(size_t)n * NH + h] = diag;
                    atomicMax(&smaxL, encf(mx));
                }
            }
            __syncthreads();
            if (tid == 0) atomicMax(&stab[h], smaxL);
        }
    }
}

// ---------------- keys pass 2: kp in-place + kpsum + packed bf16 copy ----------------
__global__ __launch_bounds__(256) void k_kp(float* __restrict__ kp, const float* __restrict__ diagK,
                                            const u32* __restrict__ stab, float* __restrict__ kpsum,
                                            u16* __restrict__ kp16)
{
    __shared__ float part[NH * MF];
    __shared__ float stabf[4];
    int tid = threadIdx.x;
    if (tid < NH * MF) part[tid] = 0.f;
    if (tid >= 128 && tid < 132) stabf[tid - 128] = decf(stab[tid - 128]);
    __syncthreads();
    int base = blockIdx.x * 64 * MF;   // 64 rows/block, exact: 1875*64 = 120000
    for (int i = tid; i < 64 * MF; i += 256) {
        int row = blockIdx.x * 64 + i / MF;
        int m = i - (i / MF) * MF;
        int h = row & 3;
        float v = RATIO * (expf(kp[base + i] - diagK[row] - stabf[h]) + 1e-6f);
        kp[base + i] = v;
        kp16[(size_t)row * 32 + m] = f2bf(v);
        atomicAdd(&part[h * MF + m], v);
    }
    if (tid < 64) {
        int row = blockIdx.x * 64 + tid;
        kp16[(size_t)row * 32 + 30] = 0;
        kp16[(size_t)row * 32 + 31] = 0;
    }
    __syncthreads();
    if (tid < NH * MF) atomicAdd(&kpsum[tid], part[tid]);
}

// ---------------- attn_norm[n,h] = qp[n,h,:] . kpsum[h,:] ----------------
__global__ __launch_bounds__(256) void k_an(const float* __restrict__ qp, const float* __restrict__ kpsum,
                                            float* __restrict__ an)
{
    __shared__ float kps[NH * MF];
    int tid = threadIdx.x;
    if (tid < NH * MF) kps[tid] = kpsum[tid];
    __syncthreads();
    int idx = blockIdx.x * 256 + tid;
    if (idx >= NN * NH) return;
    int h = idx & 3;
    const float* q = qp + (size_t)idx * MF;
    float s = 0.f;
    #pragma unroll
    for (int m = 0; m < MF; ++m) s += q[m] * kps[h * MF + m];
    an[idx] = s;
}

// ---------------- kvs via MFMA: kvs[h, km, d] = sum_n kg[n,km] * V[n,h,d] ----------------
#define KVS_CHUNKS 50
#define KVS_NPB (NN / KVS_CHUNKS)    /* 600 nodes per block */
__global__ __launch_bounds__(512) void k_kvs(const float* __restrict__ kp, const void* __restrict__ gum,
                                             const u16* __restrict__ V16, const int* __restrict__ flag,
                                             float* __restrict__ Pkvs, float* __restrict__ Pksum)
{
    __shared__ __align__(16) char kgT[320 * 128];   // 40KB bf16 [320 km][64 n] swizzled
    __shared__ __align__(16) char VT[64 * 128];     //  8KB bf16 [64 d][64 n] swizzled
    __shared__ float kpT[64][31];                    // +1 pad
    __shared__ float egT[64][10];
    const int tid = threadIdx.x;
    const int h = blockIdx.y;
    const int chunk = blockIdx.x;
    const int n0 = chunk * KVS_NPB;
    const int f32 = *flag;
    const int wave = tid >> 6, lane = tid & 63;

    float ksacc[5] = {0.f, 0.f, 0.f, 0.f, 0.f};
    f32x4 acc[10] = {};

    for (int t0 = 0; t0 < KVS_NPB; t0 += 64) {
        __syncthreads();   // prev-tile MFMA reads done
        // ---- stage kp tile (zero-pad past chunk end) ----
        for (int i = tid; i < 64 * MF; i += 512) {
            int n = i / MF, m = i - (i / MF) * MF;
            kpT[n][m] = (t0 + n < KVS_NPB) ? kp[(size_t)(n0 + t0 + n) * (NH * MF) + h * MF + m] : 0.f;
        }
        // ---- stage exp(gumbel) tile ----
        for (int i = tid; i < 64 * KG; i += 512) {
            int n = i / KG, k = i - (i / KG) * KG;
            float e = 0.f;
            if (t0 + n < KVS_NPB) {
                size_t gofs = (size_t)(n0 + t0 + n) * (NH * KG) + h * KG + k;
                float g = f32 ? ((const float*)gum)[gofs] : u2f(((const u16*)gum)[gofs]);
                e = expf(g);
            }
            egT[n][k] = e;
        }
        // ---- stage V^T tile (u16 scatter, swizzled) ----
        for (int i = tid; i < 64 * 16; i += 512) {
            int n = i >> 4, dq = (i & 15) * 4;
            u32 v0 = 0, v1 = 0;
            if (t0 + n < KVS_NPB) {
                uint2 vv = *(const uint2*)(V16 + (size_t)(n0 + t0 + n) * 256 + h * 64 + dq);
                v0 = vv.x; v1 = vv.y;
            }
            #pragma unroll
            for (int j = 0; j < 4; ++j) {
                u16 val = (u16)(((j < 2) ? v0 : v1) >> ((j & 1) * 16));
                int d = dq + j;
                *(u16*)(VT + d * 128 + ((n * 2) ^ ((d & 7) << 4))) = val;
            }
        }
        __syncthreads();
        // ---- build kgT = bf16(kp * eg); accumulate ksum from the rounded values ----
        #pragma unroll
        for (int it = 0; it < 5; ++it) {
            int idx = tid + it * 512;          // 2560 = 320 rows x 8 n-chunks
            int row = idx >> 3, nc = idx & 7;
            u32 w_[4] = {0u, 0u, 0u, 0u};
            if (row < 300) {
                int k = row / MF, m = row - (row / MF) * MF;
                float s = 0.f;
                #pragma unroll
                for (int p = 0; p < 4; ++p) {
                    int na = nc * 8 + 2 * p, nb = na + 1;
                    u16 ha = f2bf(kpT[na][m] * egT[na][k]);
                    u16 hb = f2bf(kpT[nb][m] * egT[nb][k]);
                    w_[p] = (u32)ha | ((u32)hb << 16);
                    s += u2f(ha) + u2f(hb);
                }
                ksacc[it] += s;
            }
            *(uint4*)(kgT + row * 128 + ((nc * 16) ^ ((row & 7) << 4))) = make_uint4(w_[0], w_[1], w_[2], w_[3]);
        }
        __syncthreads();
        // ---- MFMA: wave owns C-tiles ct = wave*10 + i; kt = ct/4 (km), dt = ct%4 (d) ----
        #pragma unroll
        for (int kk = 0; kk < 2; ++kk) {
            const int kb = (kk * 32 + ((lane >> 4) * 8)) * 2;
            #pragma unroll
            for (int i = 0; i < 10; ++i) {
                int ct = wave * 10 + i;
                int kt = ct >> 2, dt = ct & 3;
                int ar = kt * 16 + (lane & 15);
                bf16x8 a = *(const bf16x8*)(kgT + ar * 128 + (kb ^ ((ar & 7) << 4)));
                int br = dt * 16 + (lane & 15);
                bf16x8 b = *(const bf16x8*)(VT + br * 128 + (kb ^ ((br & 7) << 4)));
                acc[i] = __builtin_amdgcn_mfma_f32_16x16x32_bf16(a, b, acc[i], 0, 0, 0);
            }
        }
    }
    // ---- write Pkvs partials: [chunk][h][300][64] ----
    #pragma unroll
    for (int i = 0; i < 10; ++i) {
        int ct = wave * 10 + i;
        int kt = ct >> 2, dt = ct & 3;
        int col = dt * 16 + (lane & 15);
        #pragma unroll
        for (int r = 0; r < 4; ++r) {
            int row = kt * 16 + ((lane >> 4) * 4) + r;
            if (row < 300)
                Pkvs[(((size_t)chunk * NH + h) * 300 + row) * 64 + col] = acc[i][r];
        }
    }
    // ---- ksum partial: reduce across the 8 n-chunk threads of each row ----
    #pragma unroll
    for (int it = 0; it < 5; ++it) {
        float v = ksacc[it];
        v += __shfl_xor(v, 1);
        v += __shfl_xor(v, 2);
        v += __shfl_xor(v, 4);
        int row = (tid + it * 512) >> 3;
        if ((tid & 7) == 0 && row < 300)
            Pksum[chunk * 1200 + h * 300 + row] = v;
    }
}

// ---------------- reduce partials -> kvs, ksum ----------------
__global__ __launch_bounds__(256) void k_reduce(const float* __restrict__ Pkvs, const float* __restrict__ Pksum,
                                                float* __restrict__ kvs, float* __restrict__ ksum)
{
    int i = blockIdx.x * 256 + threadIdx.x;
    if (i < NH * KG * MF * DH) {
        float s = 0.f;
        for (int c = 0; c < KVS_CHUNKS; ++c) s += Pkvs[(size_t)c * (NH * 300 * 64) + i];
        kvs[i] = s;
    } else if (i < NH * KG * MF * DH + NH * KG * MF) {
        int j = i - NH * KG * MF * DH;
        float s = 0.f;
        for (int c = 0; c < KVS_CHUNKS; ++c) s += Pksum[c * 1200 + j];
        ksum[j] = s;
    }
}

// ---------------- per-edge attention weights -> link loss partials ----------------
__global__ __launch_bounds__(256) void k_edge(const int* __restrict__ ei,
                                              const u16* __restrict__ qp16, const u16* __restrict__ kp16,
                                              const float* __restrict__ an,
                                              const int* __restrict__ din, float* __restrict__ lossp)
{
    __shared__ float ls[64];
    int tid = threadIdx.x;
    int eg = tid >> 2, h = tid & 3;
    int e = blockIdx.x * 64 + eg;           // grid = NE/64 exact
    int s = ei[e], t = ei[NE + e];
    const uint4* qv = (const uint4*)(qp16 + ((size_t)t * NH + h) * 32);
    const uint4* kv = (const uint4*)(kp16 + ((size_t)s * NH + h) * 32);
    float num = 0.f;
    #pragma unroll
    for (int c = 0; c < 4; ++c) {
        uint4 a = qv[c], b = kv[c];
        num += u2f((u16)(a.x & 0xFFFF)) * u2f((u16)(b.x & 0xFFFF))
             + u2f((u16)(a.x >> 16))    * u2f((u16)(b.x >> 16))
             + u2f((u16)(a.y & 0xFFFF)) * u2f((u16)(b.y & 0xFFFF))
             + u2f((u16)(a.y >> 16))    * u2f((u16)(b.y >> 16))
             + u2f((u16)(a.z & 0xFFFF)) * u2f((u16)(b.z & 0xFFFF))
             + u2f((u16)(a.z >> 16))    * u2f((u16)(b.z >> 16))
             + u2f((u16)(a.w & 0xFFFF)) * u2f((u16)(b.w & 0xFFFF))
             + u2f((u16)(a.w >> 16))    * u2f((u16)(b.w >> 16));
    }
    float term = logf(num / an[(size_t)t * NH + h]);
    term += __shfl_xor(term, 1);
    term += __shfl_xor(term, 2);
    if (h == 0) ls[eg] = term / (float)din[t];
    __syncthreads();
    if (tid < 64) {
        float v = ls[tid];
        #pragma unroll
        for (int o = 32; o > 0; o >>= 1) v += __shfl_xor(v, o);
        if (tid == 0) atomicAdd(&lossp[blockIdx.x & 1023], v);
    }
}

// ---------------- attention readout: 48 nodes/block (3x16 sub-tiles) ----------------
#define AT_NT 48
__global__ __launch_bounds__(256) void k_attn(
    const float* __restrict__ qp, const float* __restrict__ kvs, const float* __restrict__ ksum,
    u16* __restrict__ zatt)
{
    __shared__ float qpTf[3][NH * 484];       // per 16-node sub-tile: plane h [m][j] stride 16
    __shared__ u32   kvbuf[NH * 964];         // bf16 kvs plane (stride 1928 u16); prologue alias: ksL fp32
    __shared__ float rdenL[3][16 * NH * KG];  // [sub][j][h][k]
    u16*   kvL16 = (u16*)kvbuf;
    float* ksL   = (float*)kvbuf;             // 1200 floats, dead before first kv stage
    int tid = threadIdx.x;
    int n0 = blockIdx.x * AT_NT;              // grid = NN/48 = 625 exact

    for (int i = tid; i < AT_NT * NH * MF; i += 256) {   // qp -> transposed LDS
        int j48 = i / (NH * MF); int r = i - j48 * (NH * MF);
        int h = r / MF; int m = r - h * MF;
        qpTf[j48 >> 4][h * 484 + m * 16 + (j48 & 15)] = qp[(size_t)(n0 + j48) * (NH * MF) + r];
    }
    for (int i = tid; i < NH * KG * MF; i += 256) ksL[i] = ksum[i];
    __syncthreads();
    for (int i = tid; i < AT_NT * NH * KG; i += 256) {   // rden = 1/(qp.ksum)
        int j48 = i / (NH * KG); int r = i - j48 * (NH * KG);
        int h = r / KG;
        int sub = j48 >> 4, j = j48 & 15;
        float s = 0.f;
        #pragma unroll
        for (int m = 0; m < MF; ++m) s += qpTf[sub][h * 484 + m * 16 + j] * ksL[r * MF + m];
        rdenL[sub][j * (NH * KG) + r] = 1.0f / s;
    }

    const int h  = tid >> 6;
    const int jg = (tid >> 4) & 3;
    const int dg = tid & 15;
    float acc[3][4][4] = {};
    for (int k = 0; k < KG; ++k) {
        __syncthreads();   // also protects ksL->kvL16 overlay on first iteration
        for (int i = tid; i < NH * MF * DH; i += 256) {  // stage kvs[:,k,:,:] as bf16
            int hh = i / (MF * DH); int r = i - hh * (MF * DH);
            kvL16[hh * 1928 + r] = f2bf(kvs[((size_t)(hh * 10 + k) * MF) * DH + r]);
        }
        __syncthreads();
        float ps[3][4][4] = {};
        const u16* kb = kvL16 + h * 1928 + dg * 4;
        const float* qb0 = qpTf[0] + h * 484 + jg * 4;
        const float* qb1 = qpTf[1] + h * 484 + jg * 4;
        const float* qb2 = qpTf[2] + h * 484 + jg * 4;
        #pragma unroll
        for (int m = 0; m < MF; ++m) {
            ushort4 bu = *(const ushort4*)(kb + m * 64);
            float4 b = make_float4(u2f(bu.x), u2f(bu.y), u2f(bu.z), u2f(bu.w));
            float4 a0 = *(const float4*)(qb0 + m * 16);
            float4 a1 = *(const float4*)(qb1 + m * 16);
            float4 a2 = *(const float4*)(qb2 + m * 16);
            ps[0][0][0] += a0.x * b.x; ps[0][0][1] += a0.x * b.y; ps[0][0][2] += a0.x * b.z; ps[0][0][3] += a0.x * b.w;
            ps[0][1][0] += a0.y * b.x; ps[0][1][1] += a0.y * b.y; ps[0][1][2] += a0.y * b.z; ps[0][1][3] += a0.y * b.w;
            ps[0][2][0] += a0.z * b.x; ps[0][2][1] += a0.z * b.y; ps[0][2][2] += a0.z * b.z; ps[0][2][3] += a0.z * b.w;
            ps[0][3][0] += a0.w * b.x; ps[0][3][1] += a0.w * b.y; ps[0][3][2] += a0.w * b.z; ps[0][3][3] += a0.w * b.w;
            ps[1][0][0] += a1.x * b.x; ps[1][0][1] += a1.x * b.y; ps[1][0][2] += a1.x * b.z; ps[1][0][3] += a1.x * b.w;
            ps[1][1][0] += a1.y * b.x; ps[1][1][1] += a1.y * b.y; ps[1][1][2] += a1.y * b.z; ps[1][1][3] += a1.y * b.w;
            ps[1][2][0] += a1.z * b.x; ps[1][2][1] += a1.z * b.y; ps[1][2][2] += a1.z * b.z; ps[1][2][3] += a1.z * b.w;
            ps[1][3][0] += a1.w * b.x; ps[1][3][1] += a1.w * b.y; ps[1][3][2] += a1.w * b.z; ps[1][3][3] += a1.w * b.w;
            ps[2][0][0] += a2.x * b.x; ps[2][0][1] += a2.x * b.y; ps[2][0][2] += a2.x * b.z; ps[2][0][3] += a2.x * b.w;
            ps[2][1][0] += a2.y * b.x; ps[2][1][1] += a2.y * b.y; ps[2][1][2] += a2.y * b.z; ps[2][1][3] += a2.y * b.w;
            ps[2][2][0] += a2.z * b.x; ps[2][2][1] += a2.z * b.y; ps[2][2][2] += a2.z * b.z; ps[2][2][3] += a2.z * b.w;
            ps[2][3][0] += a2.w * b.x; ps[2][3][1] += a2.w * b.y; ps[2][3][2] += a2.w * b.z; ps[2][3][3] += a2.w * b.w;
        }
        #pragma unroll
        for (int sub = 0; sub < 3; ++sub)
            #pragma unroll
            for (int j4 = 0; j4 < 4; ++j4) {
                float rd = rdenL[sub][(jg * 4 + j4) * (NH * KG) + h * KG + k];
                #pragma unroll
                for (int d4 = 0; d4 < 4; ++d4) acc[sub][j4][d4] += ps[sub][j4][d4] * rd;
            }
    }
    #pragma unroll
    for (int sub = 0; sub < 3; ++sub)
        #pragma unroll
        for (int j4 = 0; j4 < 4; ++j4) {
            int n = n0 + sub * 16 + jg * 4 + j4;
            #pragma unroll
            for (int d4 = 0; d4 < 4; ++d4)
                zatt[(size_t)n * 256 + h * 64 + dg * 4 + d4] = f2bf(acc[sub][j4][d4] * (1.0f / KG));
        }
}

// ---------------- conv gather: wave-per-node, zero barriers ----------------
__global__ __launch_bounds__(256) void k_gather(
    const u16* __restrict__ zatt, const u16* __restrict__ V16,
    const int* __restrict__ csr, const float* __restrict__ wedge,
    const int* __restrict__ offn, const int* __restrict__ din,
    const float* __restrict__ params, u16* __restrict__ pre)
{
    int tid = threadIdx.x;
    int w = tid >> 6, l = tid & 63;
    int n = blockIdx.x * 4 + w;             // grid = NN/4 = 7500 exact
    float sigb = 1.f / (1.f + expf(-params[P_BBF + (l >> 4)]));   // head of elems l*4..l*4+3
    int dn = din[n], o0 = offn[n];
    float c0 = 0.f, c1 = 0.f, c2 = 0.f, c3 = 0.f;
    for (int t0 = 0; t0 < dn; t0 += 64) {
        int cnt = min(64, dn - t0);
        int myIdx = 0; float myW = 0.f;
        if (l < cnt) { myIdx = csr[o0 + t0 + l]; myW = wedge[o0 + t0 + l]; }
        int j = 0;
        for (; j + 7 < cnt; j += 8) {       // 8 rows in flight (wave-uniform trip count)
            int   s0 = __shfl(myIdx, j),     s1 = __shfl(myIdx, j + 1);
            int   s2 = __shfl(myIdx, j + 2), s3 = __shfl(myIdx, j + 3);
            int   s4 = __shfl(myIdx, j + 4), s5 = __shfl(myIdx, j + 5);
            int   s6 = __shfl(myIdx, j + 6), s7 = __shfl(myIdx, j + 7);
            float w0 = __shfl(myW, j),     w1 = __shfl(myW, j + 1);
            float w2 = __shfl(myW, j + 2), w3 = __shfl(myW, j + 3);
            float w4 = __shfl(myW, j + 4), w5 = __shfl(myW, j + 5);
            float w6 = __shfl(myW, j + 6), w7 = __shfl(myW, j + 7);
            uint2 a0 = *(const uint2*)(V16 + (size_t)s0 * 256 + l * 4);
            uint2 a1 = *(const uint2*)(V16 + (size_t)s1 * 256 + l * 4);
            uint2 a2 = *(const uint2*)(V16 + (size_t)s2 * 256 + l * 4);
            uint2 a3 = *(const uint2*)(V16 + (size_t)s3 * 256 + l * 4);
            uint2 a4 = *(const uint2*)(V16 + (size_t)s4 * 256 + l * 4);
            uint2 a5 = *(const uint2*)(V16 + (size_t)s5 * 256 + l * 4);
            uint2 a6 = *(const uint2*)(V16 + (size_t)s6 * 256 + l * 4);
            uint2 a7 = *(const uint2*)(V16 + (size_t)s7 * 256 + l * 4);
            c0 += w0 * u2f((u16)(a0.x & 0xFFFF)) + w1 * u2f((u16)(a1.x & 0xFFFF))
                + w2 * u2f((u16)(a2.x & 0xFFFF)) + w3 * u2f((u16)(a3.x & 0xFFFF))
                + w4 * u2f((u16)(a4.x & 0xFFFF)) + w5 * u2f((u16)(a5.x & 0xFFFF))
                + w6 * u2f((u16)(a6.x & 0xFFFF)) + w7 * u2f((u16)(a7.x & 0xFFFF));
            c1 += w0 * u2f((u16)(a0.x >> 16)) + w1 * u2f((u16)(a1.x >> 16))
                + w2 * u2f((u16)(a2.x >> 16)) + w3 * u2f((u16)(a3.x >> 16))
                + w4 * u2f((u16)(a4.x >> 16)) + w5 * u2f((u16)(a5.x >> 16))
                + w6 * u2f((u16)(a6.x >> 16)) + w7 * u2f((u16)(a7.x >> 16));
            c2 += w0 * u2f((u16)(a0.y & 0xFFFF)) + w1 * u2f((u16)(a1.y & 0xFFFF))
                + w2 * u2f((u16)(a2.y & 0xFFFF)) + w3 * u2f((u16)(a3.y & 0xFFFF))
                + w4 * u2f((u16)(a4.y & 0xFFFF)) + w5 * u2f((u16)(a5.y & 0xFFFF))
                + w6 * u2f((u16)(a6.y & 0xFFFF)) + w7 * u2f((u16)(a7.y & 0xFFFF));
            c3 += w0 * u2f((u16)(a0.y >> 16)) + w1 * u2f((u16)(a1.y >> 16))
                + w2 * u2f((u16)(a2.y >> 16)) + w3 * u2f((u16)(a3.y >> 16))
                + w4 * u2f((u16)(a4.y >> 16)) + w5 * u2f((u16)(a5.y >> 16))
                + w6 * u2f((u16)(a6.y >> 16)) + w7 * u2f((u16)(a7.y >> 16));
        }
        for (; j < cnt; ++j) {
            int   s0 = __shfl(myIdx, j);
            float w0 = __shfl(myW, j);
            uint2 a0 = *(const uint2*)(V16 + (size_t)s0 * 256 + l * 4);
            c0 += w0 * u2f((u16)(a0.x & 0xFFFF));
            c1 += w0 * u2f((u16)(a0.x >> 16));
            c2 += w0 * u2f((u16)(a0.y & 0xFFFF));
            c3 += w0 * u2f((u16)(a0.y >> 16));
        }
    }
    uint2 za = *(const uint2*)(zatt + (size_t)n * 256 + l * 4);
    float e0 = u2f((u16)(za.x & 0xFFFF)) + sigb * c0;
    float e1 = u2f((u16)(za.x >> 16))    + sigb * c1;
    float e2 = u2f((u16)(za.y & 0xFFFF)) + sigb * c2;
    float e3 = u2f((u16)(za.y >> 16))    + sigb * c3;
    uint2 r;
    r.x = (u32)f2bf(e0) | ((u32)f2bf(e1) << 16);
    r.y = (u32)f2bf(e2) | ((u32)f2bf(e3) << 16);
    *(uint2*)(pre + (size_t)n * 256 + l * 4) = r;
}

// ---------------- out = pre(bf16) x Wo^T via MFMA (Wo hi/lo split on the fly) ----------------
__global__ __launch_bounds__(256) void k_out(
    const u16* __restrict__ pre, const float* __restrict__ params, float* __restrict__ out)
{
    __shared__ __align__(16) char smemc[24576];   // As(8KB) | BsH(8KB) | BsL(8KB)
    char* As  = smemc;
    char* BsH = smemc + 8192;
    char* BsL = smemc + 16384;
    const int tid = threadIdx.x;
    const int bm = blockIdx.x * 64;
    const int wave = tid >> 6, lane = tid & 63;
    const int wm = wave >> 1, wn = wave & 1;
    const int sr = tid >> 2;
    const int sc = (tid & 3) * 16;

    f32x4 acc[2][2] = {};

    for (int k0 = 0; k0 < 256; k0 += 64) {
        __syncthreads();
        int byt0 = sr * 128 + (((sc + 0) * 2) ^ ((sr & 7) << 4));
        int byt1 = sr * 128 + (((sc + 8) * 2) ^ ((sr & 7) << 4));
        {   // ---- stage A: pre rows (bf16 copy) ----
            int row = bm + sr;
            uint4 v0 = make_uint4(0, 0, 0, 0), v1 = v0;
            if (row < NN) {
                const uint4* p = (const uint4*)(pre + (size_t)row * 256 + k0 + sc);
                v0 = p[0]; v1 = p[1];
            }
            *(uint4*)(As + byt0) = v0;
            *(uint4*)(As + byt1) = v1;
        }
        {   // ---- stage B: Wo fp32 -> hi/lo bf16 planes ----
            float x[16];
            const float4* wr = (const float4*)(params + P_WOF + (size_t)sr * 256 + k0 + sc);
            #pragma unroll
            for (int q4 = 0; q4 < 4; ++q4) {
                float4 v = wr[q4];
                x[q4 * 4 + 0] = v.x; x[q4 * 4 + 1] = v.y;
                x[q4 * 4 + 2] = v.z; x[q4 * 4 + 3] = v.w;
            }
            #pragma unroll
            for (int j8 = 0; j8 < 2; ++j8) {
                u32 hw[4], lw[4];
                #pragma unroll
                for (int p = 0; p < 4; ++p) {
                    float a = x[j8 * 8 + 2 * p], b2 = x[j8 * 8 + 2 * p + 1];
                    u16 ha = f2bf(a), hb = f2bf(b2);
                    hw[p] = (u32)ha | ((u32)hb << 16);
                    u16 la = f2bf(a - u2f(ha)), lb = f2bf(b2 - u2f(hb));
                    lw[p] = (u32)la | ((u32)lb << 16);
                }
                int byt = sr * 128 + (((sc + j8 * 8) * 2) ^ ((sr & 7) << 4));
                *(uint4*)(BsH + byt) = make_uint4(hw[0], hw[1], hw[2], hw[3]);
                *(uint4*)(BsL + byt) = make_uint4(lw[0], lw[1], lw[2], lw[3]);
            }
        }
        __syncthreads();
        #pragma unroll
        for (int kk = 0; kk < 2; ++kk) {
            const int kb = (kk * 32 + ((lane >> 4) * 8)) * 2;
            bf16x8 a[2], bh[2], bl[2];
            #pragma unroll
            for (int i = 0; i < 2; ++i) {
                int ar = 32 * wm + 16 * i + (lane & 15);
                int ab = ar * 128 + (kb ^ ((ar & 7) << 4));
                a[i] = *(const bf16x8*)(As + ab);
                int br = 32 * wn + 16 * i + (lane & 15);
                int bb2 = br * 128 + (kb ^ ((br & 7) << 4));
                bh[i] = *(const bf16x8*)(BsH + bb2);
                bl[i] = *(const bf16x8*)(BsL + bb2);
            }
            #pragma unroll
            for (int i = 0; i < 2; ++i)
                #pragma unroll
                for (int nf = 0; nf < 2; ++nf) {
                    acc[i][nf] = __builtin_amdgcn_mfma_f32_16x16x32_bf16(a[i], bh[nf], acc[i][nf], 0, 0, 0);
                    acc[i][nf] = __builtin_amdgcn_mfma_f32_16x16x32_bf16(a[i], bl[nf], acc[i][nf], 0, 0, 0);
                }
        }
    }
    #pragma unroll
    for (int i = 0; i < 2; ++i)
        #pragma unroll
        for (int nf = 0; nf < 2; ++nf) {
            int col = 32 * wn + 16 * nf + (lane & 15);
            float bias = params[P_WOBF + col];
            #pragma unroll
            for (int r2 = 0; r2 < 4; ++r2) {
                int row = bm + 32 * wm + 16 * i + ((lane >> 4) * 4) + r2;
                if (row < NN) out[(size_t)row * 64 + col] = acc[i][nf][r2] + bias;
            }
        }
}

// ---------------- loss finalize ----------------
__global__ __launch_bounds__(256) void k_loss(const float* __restrict__ lossp, float* __restrict__ out) {
    __shared__ float s[256];
    int tid = threadIdx.x;
    float v = 0.f;
    for (int i = tid; i < 1024; i += 256) v += lossp[i];
    s[tid] = v;
    __syncthreads();
    for (int o = 128; o > 0; o >>= 1) {
        if (tid < o) s[tid] += s[tid + o];
        __syncthreads();
    }
    if (tid == 0) out[(size_t)NN * 64] = s[0] / (float)(NE * NH);   // fp32 output
}

extern "C" void kernel_launch(void* const* d_in, const int* in_sizes, int n_in,
                              void* d_out, int out_size, void* d_ws, size_t ws_size,
                              hipStream_t stream)
{
    const void* z    = d_in[0];
    const int*  ei   = (const int*)d_in[1];
    const void* taup = d_in[2];
    const void* gum  = d_in[3];
    const void* proj = d_in[4];
    const void* Wq   = d_in[5];
    const void* bq   = d_in[6];
    const void* Wk   = d_in[7];
    const void* bk   = d_in[8];
    const void* Wv   = d_in[9];
    const void* bv   = d_in[10];
    const void* Wo   = d_in[11];
    const void* Wob  = d_in[12];
    const void* bb   = d_in[13];
    float* out = (float*)d_out;

    // ---- workspace carve-up (fp32 units), total ~67 MB ----
    u16*   V16    = (u16*)d_ws;                    //  7,680,000 u16 : [N,256] bf16 V
    float* qpb    = (float*)d_ws + 3840000;        //  3,600,000 : [N,H,M]
    float* kpb    = qpb + (size_t)NN * NH * MF;    //  3,600,000 : dashK then kp in-place
    float* diagK  = kpb + (size_t)NN * NH * MF;    //    120,000
    float* anb    = diagK + (size_t)NN * NH;       //    120,000
    u16*   zatt   = (u16*)kpb;                     //  reuses kpb+diagK+anb (dead after k_edge)
    int*   csr    = (int*)(anb + (size_t)NN * NH); //    480,000
    int*   offn   = csr + NE;                      //     30,000
    float* params = (float*)(offn + NN);           //    215,749 (+pad to 215,752)
    // ---- zeroed accumulator region ----
    float* kvs    = params + 215752;               //     76,800 : [H,K,M,D]
    float* ksum   = kvs + NH * KG * MF * DH;       //      1,200 : [H,K,M]
    float* kpsum  = ksum + NH * KG * MF;           //        120 : [H,M]
    int*   din    = (int*)(kpsum + NH * MF);       //     30,000
    int*   doutd  = din + NN;                      //     30,000
    int*   fill   = doutd + NN;                    //     30,000
    int*   counter = fill + NN;                    //          4
    u32*   stab   = (u32*)(counter + 4);           //          4
    float* lossp  = (float*)(stab + 4);            //      1,024
    int*   flag   = (int*)(lossp + 1024);          //          4
    float* wedge  = (float*)(flag + 4);            //    480,000 (not zeroed; fully written)
    u16*   qp16   = (u16*)(wedge + NE);            //  3,840,000 u16 : [N,H,32] bf16 qp
    u16*   kp16   = qp16 + (size_t)NN * NH * 32;   //  3,840,000 u16 : [N,H,32] bf16 kp
    // kvs partials overlay qp16+kp16 (15.36 MB, exact fit: 50*4*300*64 floats);
    // alive only between k_kvs and k_reduce, after qp16/kp16's last reader (k_edge).
    float* Pkvs   = (float*)qp16;
    float* Pksum  = (float*)(kp16 + (size_t)NN * NH * 32);   //  60,000 floats (new tail)
    // W hi/lo bf16 planes overlay kp16 (dead until k_kp writes it, after k_gemm_feat)
    u16*   Whb    = kp16;                          //    196,608 u16 : [768][256] W hi
    u16*   Wlb    = kp16 + 196608;                 //    196,608 u16 : [768][256] W lo
    // pre[N,256] bf16 overlays qp16+kp16 (7,680,000 u16 exactly); alive only
    // between k_gather and k_out, after Pkvs's last reader (k_reduce).
    u16*   pre    = qp16;
    size_t zero_bytes = (size_t)((char*)(flag + 4) - (char*)kvs);

    hipMemsetAsync(kvs, 0, zero_bytes, stream);

    k_detect<<<dim3(1), dim3(64), 0, stream>>>((const u16*)z, flag);
    k_cvt_params<<<dim3((P_TOTAL + 255) / 256), dim3(256), 0, stream>>>(
        Wq, Wk, Wv, bq, bk, bv, Wo, Wob, bb, proj, taup, params, flag);
    k_cvt_w<<<dim3(768), dim3(256), 0, stream>>>(params, Whb, Wlb);

    k_deg <<<dim3((NE + 255) / 256), dim3(256), 0, stream>>>(ei, din, doutd);
    k_off <<<dim3((NN + 255) / 256), dim3(256), 0, stream>>>(din, offn, counter);
    k_fill<<<dim3((NE + 255) / 256), dim3(256), 0, stream>>>(ei, offn, fill, csr, din, doutd, wedge);
    k_gemm_feat<<<dim3((NN + 63) / 64), dim3(256), 0, stream>>>(
        z, params, flag, Whb, Wlb, V16, qpb, qp16, kpb, diagK, stab);
    k_kp  <<<dim3(NN * NH / 64), dim3(256), 0, stream>>>(kpb, diagK, stab, kpsum, kp16);
    k_an  <<<dim3((NN * NH + 255) / 256), dim3(256), 0, stream>>>(qpb, kpsum, anb);
    k_edge<<<dim3(NE / 64), dim3(256), 0, stream>>>(ei, qp16, kp16, anb, din, lossp);
    // qp16/kp16 dead from here; Pkvs overlays them (stream-ordered)
    k_kvs <<<dim3(KVS_CHUNKS, NH), dim3(512), 0, stream>>>(kpb, gum, V16, flag, Pkvs, Pksum);
    k_reduce<<<dim3((NH * KG * MF * DH + NH * KG * MF + 255) / 256), dim3(256), 0, stream>>>(
        Pkvs, Pksum, kvs, ksum);
    // zatt overwrites kpb/diagK/anb from here on (stream-ordered after their last readers)
    k_attn<<<dim3(NN / AT_NT), dim3(256), 0, stream>>>(qpb, kvs, ksum, zatt);
    // pre overlays qp16/kp16 (Pkvs dead after k_reduce)
    k_gather<<<dim3(NN / 4), dim3(256), 0, stream>>>(zatt, V16, csr, wedge, offn, din, params, pre);
    k_out<<<dim3((NN + 63) / 64), dim3(256), 0, stream>>>(pre, params, out);
    k_loss<<<dim3(1), dim3(256), 0, stream>>>(lossp, out);
}

// Round 16
// 653.694 us; speedup vs baseline: 1.1331x; 1.0336x over previous
//
#include <hip/hip_runtime.h>
#include <hip/hip_bf16.h>

#define NN 30000
#define NE 480000
#define NH 4
#define DH 64
#define MF 30
#define KG 10
#define RATIO 0.18257418583505536f   /* 1/sqrt(30) */
#define DNRM  0.35355339059327373f   /* 64^-0.25  */

// fp32 params block layout (element offsets)
#define P_WF    0        /* [768][256] Wq|Wk|Wv rows */
#define P_BF    196608   /* [768] bq|bk|bv */
#define P_WOF   197376   /* [64][256] Wo */
#define P_WOBF  213760   /* [64] Wo bias */
#define P_BBF   213824   /* [4] rb bias b */
#define P_PROJ  213828   /* [30][64] proj */
#define P_TAU   215748   /* scalar */
#define P_TOTAL 215749

typedef unsigned short u16;
typedef unsigned int   u32;
typedef __attribute__((ext_vector_type(8))) short bf16x8;
typedef __attribute__((ext_vector_type(4))) float f32x4;

__device__ __forceinline__ float u2f(u16 u) { return __uint_as_float(((u32)u) << 16); }
__device__ __forceinline__ u16  f2bf(float f) {  // round-to-nearest-even bf16
    u32 x = __float_as_uint(f);
    return (u16)((x + 0x7FFFu + ((x >> 16) & 1u)) >> 16);
}
// order-preserving float->uint encoding for atomicMax over signed floats
__device__ __forceinline__ u32  encf(float f) { u32 u = __float_as_uint(f); return (u & 0x80000000u) ? ~u : (u | 0x80000000u); }
__device__ __forceinline__ float decf(u32 u)  { return (u & 0x80000000u) ? __uint_as_float(u & 0x7FFFFFFFu) : __uint_as_float(~u); }

// ---------------- dtype detection (fp32 vs bf16 input tensors) ----------------
__global__ void k_detect(const u16* __restrict__ z, int* __restrict__ flag) {
    if (threadIdx.x == 0 && blockIdx.x == 0) {
        int bad = 0;
        for (int i = 0; i < 256; i += 2) {
            u16 u = z[i];
            int e = (u >> 7) & 0xFF;
            if (u != 0 && !(e >= 100 && e <= 140)) bad++;
        }
        *flag = (bad > 16) ? 1 : 0;   // 1 = inputs are fp32
    }
}

// ---------------- stage all small params to fp32 ----------------
__global__ __launch_bounds__(256) void k_cvt_params(
    const void* Wq, const void* Wk, const void* Wv,
    const void* bq, const void* bk, const void* bv,
    const void* Wo, const void* Wob, const void* bb, const void* proj,
    const void* taup, float* __restrict__ params, const int* __restrict__ flag)
{
    int i = blockIdx.x * 256 + threadIdx.x;
    if (i >= P_TOTAL) return;
    int f = *flag;
    if (i == P_TAU) {
        float v = f ? ((const float*)taup)[0] : u2f(((const u16*)taup)[0]);
        if (!(v > 1e-6f && v < 1e6f)) {
            float ff = ((const float*)taup)[0];
            v = (ff > 1e-6f && ff < 1e6f) ? ff : 0.25f;
        }
        params[i] = v;
        return;
    }
    const void* src; int j;
    if      (i < 65536)  { src = Wq;  j = i; }
    else if (i < 131072) { src = Wk;  j = i - 65536; }
    else if (i < 196608) { src = Wv;  j = i - 131072; }
    else if (i < 196864) { src = bq;  j = i - 196608; }
    else if (i < 197120) { src = bk;  j = i - 196864; }
    else if (i < 197376) { src = bv;  j = i - 197120; }
    else if (i < 213760) { src = Wo;  j = i - 197376; }
    else if (i < 213824) { src = Wob; j = i - 213760; }
    else if (i < 213828) { src = bb;  j = i - 213824; }
    else                 { src = proj; j = i - P_PROJ; }
    params[i] = f ? ((const float*)src)[j] : u2f(((const u16*)src)[j]);
}

// ---------------- hi/lo bf16 split of W (once; gemm staging becomes pure copy) ----------------
__global__ __launch_bounds__(256) void k_cvt_w(const float* __restrict__ params,
                                               u16* __restrict__ Wh, u16* __restrict__ Wl)
{
    int i = blockIdx.x * 256 + threadIdx.x;   // grid = 768 blocks, 196608 exact
    float x = params[P_WF + i];
    u16 h = f2bf(x);
    Wh[i] = h;
    Wl[i] = f2bf(x - u2f(h));
}

// ---------------- degrees ----------------
__global__ __launch_bounds__(256) void k_deg(const int* __restrict__ ei, int* __restrict__ din, int* __restrict__ dout) {
    int e = blockIdx.x * 256 + threadIdx.x;
    if (e >= NE) return;
    atomicAdd(&dout[ei[e]], 1);
    atomicAdd(&din[ei[NE + e]], 1);
}

// ---------------- scan-free CSR offsets ----------------
__global__ __launch_bounds__(256) void k_off(const int* __restrict__ din, int* __restrict__ offn, int* __restrict__ counter) {
    __shared__ int s[256];
    __shared__ int base;
    int tid = threadIdx.x;
    int n = blockIdx.x * 256 + tid;
    int v = (n < NN) ? din[n] : 0;
    s[tid] = v;
    __syncthreads();
    for (int o = 1; o < 256; o <<= 1) {
        int t = (tid >= o) ? s[tid - o] : 0;
        __syncthreads();
        s[tid] += t;
        __syncthreads();
    }
    if (tid == 255) base = atomicAdd(counter, s[255]);
    __syncthreads();
    if (n < NN) offn[n] = base + s[tid] - v;
}

// fill CSR + precompute per-edge conv weight w = rsqrt(din[t]*dout[s])
__global__ __launch_bounds__(256) void k_fill(const int* __restrict__ ei, const int* __restrict__ offn,
                                              int* __restrict__ fill, int* __restrict__ csr,
                                              const int* __restrict__ din, const int* __restrict__ dout,
                                              float* __restrict__ wedge) {
    int e = blockIdx.x * 256 + threadIdx.x;
    if (e >= NE) return;
    int s = ei[e], t = ei[NE + e];
    int pos = offn[t] + atomicAdd(&fill[t], 1);
    csr[pos] = s;
    wedge[pos] = rsqrtf((float)din[t] * (float)dout[s]);
}

// ---------------- fused QKV GEMM + Performer epilogue (register-A, 12-panel loop) ----------------
// Round 27: baseline structure (r8/r13, 672.8-676.8us) with ONE surgical change:
// loop INTERCHANGE in the epilogue dm dot-product. The m-loop's runtime trip
// count prevented CSE, so trow[] (64 floats) was re-read from LDS for each of
// 8 m's (1024 ds_read_b32/thread/panel -- the validated r13 bottleneck). Now d
// is outer: each trow[d] read once, 8 guarded FMAs inner -> ~544 reads, ~1.9x
// cut in the dominant LDS stream. Per-dm accumulation stays d-sequential ->
// bit-identical. Zero new arrays/vec temps (r14's VGPR-tier trap avoided).
__global__ __launch_bounds__(256) void k_gemm_feat(
    const void* __restrict__ zv, const float* __restrict__ params, const int* __restrict__ flag,
    const u16* __restrict__ Wh, const u16* __restrict__ Wl,
    u16* __restrict__ V16, float* __restrict__ qp, u16* __restrict__ qp16,
    float* __restrict__ dashK, float* __restrict__ diagK, u32* __restrict__ stab)
{
    __shared__ __align__(16) char AsH[64 * 128];   // A hi chunk plane (128B rows)
    __shared__ __align__(16) char AsL[64 * 128];   // A lo chunk plane
    __shared__ __align__(16) char BsH[64 * 128];   // B hi chunk plane
    __shared__ __align__(16) char BsL[64 * 128];   // B lo chunk plane
    __shared__ float tile[64 * 68];
    __shared__ float projL[30 * 65];
    __shared__ u32 smaxL;

    const int tid = threadIdx.x;
    const int bm = blockIdx.x * 64;
    const int f32 = *flag;
    const int wave = tid >> 6, lane = tid & 63;
    const int wm = wave >> 1, wn = wave & 1;     // 2x2 wave grid, each wave 32x32
    const int sr = tid >> 2;                     // staging row 0..63
    const int sc = (tid & 3) * 16;               // staging col base

    // ---------- load + hi/lo split this thread's 64 A elements, ONCE ----------
    u32 ah[32], al[32];                          // [chunk*8 + j8*4 + p]
    {
        int zrow = bm + sr;
        if (f32) {
            #pragma unroll
            for (int c = 0; c < 4; ++c) {
                float x[16];
                if (zrow < NN) {
                    const float4* zp = (const float4*)((const float*)zv + (size_t)zrow * 256 + c * 64 + sc);
                    #pragma unroll
                    for (int q4 = 0; q4 < 4; ++q4) {
                        float4 v = zp[q4];
                        x[q4 * 4 + 0] = v.x; x[q4 * 4 + 1] = v.y;
                        x[q4 * 4 + 2] = v.z; x[q4 * 4 + 3] = v.w;
                    }
                } else {
                    #pragma unroll
                    for (int j = 0; j < 16; ++j) x[j] = 0.f;
                }
                #pragma unroll
                for (int j8 = 0; j8 < 2; ++j8)
                    #pragma unroll
                    for (int p = 0; p < 4; ++p) {
                        float a = x[j8 * 8 + 2 * p], b2 = x[j8 * 8 + 2 * p + 1];
                        u16 ha = f2bf(a), hb = f2bf(b2);
                        ah[c * 8 + j8 * 4 + p] = (u32)ha | ((u32)hb << 16);
                        u16 la = f2bf(a - u2f(ha)), lb = f2bf(b2 - u2f(hb));
                        al[c * 8 + j8 * 4 + p] = (u32)la | ((u32)lb << 16);
                    }
            }
        } else {
            #pragma unroll
            for (int c = 0; c < 4; ++c) {
                uint4 v0 = make_uint4(0, 0, 0, 0), v1 = v0;
                if (zrow < NN) {
                    const uint4* zp = (const uint4*)((const u16*)zv + (size_t)zrow * 256 + c * 64 + sc);
                    v0 = zp[0]; v1 = zp[1];
                }
                ah[c * 8 + 0] = v0.x; ah[c * 8 + 1] = v0.y; ah[c * 8 + 2] = v0.z; ah[c * 8 + 3] = v0.w;
                ah[c * 8 + 4] = v1.x; ah[c * 8 + 5] = v1.y; ah[c * 8 + 6] = v1.z; ah[c * 8 + 7] = v1.w;
            }
        }
    }
    for (int i2 = tid; i2 < MF * DH; i2 += 256) projL[(i2 >> 6) * 65 + (i2 & 63)] = params[P_PROJ + i2];

    const float* bfv = params + P_BF;
    float scale = DNRM * rsqrtf(params[P_TAU]);
    const int byt0 = sr * 128 + (((sc + 0) * 2) ^ ((sr & 7) << 4));
    const int byt1 = sr * 128 + (((sc + 8) * 2) ^ ((sr & 7) << 4));

    for (int bny = 0; bny < 12; ++bny) {
        const int bn = bny * 64;
        f32x4 acc[2][2] = {};
        #pragma unroll
        for (int k0c = 0; k0c < 4; ++k0c) {
            const int k0 = k0c * 64;
            __syncthreads();   // prev chunk (or prev panel tail) reads done
            // ---- A chunk from registers ----
            *(uint4*)(AsH + byt0) = make_uint4(ah[k0c * 8 + 0], ah[k0c * 8 + 1], ah[k0c * 8 + 2], ah[k0c * 8 + 3]);
            *(uint4*)(AsH + byt1) = make_uint4(ah[k0c * 8 + 4], ah[k0c * 8 + 5], ah[k0c * 8 + 6], ah[k0c * 8 + 7]);
            if (f32) {
                *(uint4*)(AsL + byt0) = make_uint4(al[k0c * 8 + 0], al[k0c * 8 + 1], al[k0c * 8 + 2], al[k0c * 8 + 3]);
                *(uint4*)(AsL + byt1) = make_uint4(al[k0c * 8 + 4], al[k0c * 8 + 5], al[k0c * 8 + 6], al[k0c * 8 + 7]);
            }
            // ---- B chunk (pure copy from preconverted W hi/lo) ----
            {
                const uint4* wh4 = (const uint4*)(Wh + (size_t)(bn + sr) * 256 + k0 + sc);
                *(uint4*)(BsH + byt0) = wh4[0];
                *(uint4*)(BsH + byt1) = wh4[1];
                if (f32) {
                    const uint4* wl4 = (const uint4*)(Wl + (size_t)(bn + sr) * 256 + k0 + sc);
                    *(uint4*)(BsL + byt0) = wl4[0];
                    *(uint4*)(BsL + byt1) = wl4[1];
                }
            }
            __syncthreads();
            // ---- MFMA: 2 k-steps of 32 ----
            #pragma unroll
            for (int kk = 0; kk < 2; ++kk) {
                const int kb = (kk * 32 + ((lane >> 4) * 8)) * 2;
                bf16x8 ahf[2], bhf[2], alf[2], blf[2];
                #pragma unroll
                for (int i = 0; i < 2; ++i) {
                    int ar = 32 * wm + 16 * i + (lane & 15);
                    int ab = ar * 128 + (kb ^ ((ar & 7) << 4));
                    ahf[i] = *(const bf16x8*)(AsH + ab);
                    int br = 32 * wn + 16 * i + (lane & 15);
                    int bb2 = br * 128 + (kb ^ ((br & 7) << 4));
                    bhf[i] = *(const bf16x8*)(BsH + bb2);
                    if (f32) {
                        alf[i] = *(const bf16x8*)(AsL + ab);
                        blf[i] = *(const bf16x8*)(BsL + bb2);
                    }
                }
                #pragma unroll
                for (int i = 0; i < 2; ++i)
                    #pragma unroll
                    for (int nf = 0; nf < 2; ++nf) {
                        acc[i][nf] = __builtin_amdgcn_mfma_f32_16x16x32_bf16(ahf[i], bhf[nf], acc[i][nf], 0, 0, 0);
                        if (f32) {
                            acc[i][nf] = __builtin_amdgcn_mfma_f32_16x16x32_bf16(ahf[i], blf[nf], acc[i][nf], 0, 0, 0);
                            acc[i][nf] = __builtin_amdgcn_mfma_f32_16x16x32_bf16(alf[i], bhf[nf], acc[i][nf], 0, 0, 0);
                        }
                    }
            }
        }
        // ---- epilogue for this panel (tile/projL regions untouched by staging) ----
        if (bny >= 8) {   // V panel: acc -> tile (+bias) -> coalesced bf16 store
            #pragma unroll
            for (int i = 0; i < 2; ++i)
                #pragma unroll
                for (int nf = 0; nf < 2; ++nf) {
                    int col = 32 * wn + 16 * nf + (lane & 15);
                    float bias = bfv[bn + col];
                    #pragma unroll
                    for (int r2 = 0; r2 < 4; ++r2) {
                        int row = 32 * wm + 16 * i + ((lane >> 4) * 4) + r2;
                        tile[row * 68 + col] = acc[i][nf][r2] + bias;
                    }
                }
            __syncthreads();
            for (int i2 = tid; i2 < 4096; i2 += 256) {
                int row = i2 >> 6, col = i2 & 63;
                int nrow = bm + row;
                if (nrow < NN) V16[(size_t)nrow * 256 + (bn - 512) + col] = f2bf(tile[row * 68 + col]);
            }
            continue;
        }

        // Q/K panels: performer features on the 64x64 head tile
        if (tid == 0) smaxL = 0u;
        #pragma unroll
        for (int i = 0; i < 2; ++i)
            #pragma unroll
            for (int nf = 0; nf < 2; ++nf) {
                int col = 32 * wn + 16 * nf + (lane & 15);
                float bias = bfv[bn + col];
                #pragma unroll
                for (int r2 = 0; r2 < 4; ++r2) {
                    int row = 32 * wm + 16 * i + ((lane >> 4) * 4) + r2;
                    tile[row * 68 + col] = (acc[i][nf][r2] + bias) * scale;
                }
            }
        __syncthreads();

        int r = tid >> 2, q = tid & 3;      // 4 lanes cooperate per row; same wave
        int n = bm + r;
        const float* trow = tile + r * 68;
        float dp = 0.f;
        #pragma unroll
        for (int d = q * 16; d < q * 16 + 16; ++d) dp += trow[d] * trow[d];
        dp += __shfl_xor(dp, 1);
        dp += __shfl_xor(dp, 2);
        float diag = dp * 0.5f;

        // dm dot products, loop-interchanged: trow[d] read ONCE per d (was 8x).
        // Per-dm accumulation remains d-sequential 0..63 -> bit-identical.
        float dm[8];
        #pragma unroll
        for (int i = 0; i < 8; ++i) dm[i] = 0.f;
        for (int d = 0; d < DH; ++d) {
            float t = trow[d];
            #pragma unroll
            for (int i = 0; i < 8; ++i) {
                int m = q + 4 * i;
                if (m < MF) dm[i] += t * projL[m * 65 + d];
            }
        }
        float lmax = -3.0e38f;
        #pragma unroll
        for (int i = 0; i < 8; ++i) {
            int m = q + 4 * i;
            if (m < MF) lmax = fmaxf(lmax, dm[i]);
        }
        float mx = fmaxf(lmax, __shfl_xor(lmax, 1));
        mx = fmaxf(mx, __shfl_xor(mx, 2));

        if (bny < 4) {   // Q: row-local stab, write qp (fp32) + packed bf16 copy
            int h = bny;
            if (n < NN) {
                float* o = qp + ((size_t)n * NH + h) * MF;
                u16* o16 = qp16 + ((size_t)n * NH + h) * 32;
                int nm = 0;
                for (int m = q; m < MF; m += 4) {
                    float v = RATIO * (expf(dm[nm++] - diag - mx) + 1e-6f);
                    o[m] = v;
                    o16[m] = f2bf(v);
                }
                if (q == 0) { o16[30] = 0; o16[31] = 0; }
            }
        } else {          // K: store dash/diag, global per-head max
            int h = bny - 4;
            if (n < NN) {
                float* o = dashK + ((size_t)n * NH + h) * MF;
                int nm = 0;
                for (int m = q; m < MF; m += 4) o[m] = dm[nm++];
                if (q == 0) {
                    diagK[(size_t)n * NH + h] = diag;
                    atomicMax(&smaxL, encf(mx));
                }
            }
            __syncthreads();
            if (tid == 0) atomicMax(&stab[h], smaxL);
        }
    }
}

// ---------------- keys pass 2: kp in-place + kpsum + packed bf16 copy ----------------
__global__ __launch_bounds__(256) void k_kp(float* __restrict__ kp, const float* __restrict__ diagK,
                                            const u32* __restrict__ stab, float* __restrict__ kpsum,
                                            u16* __restrict__ kp16)
{
    __shared__ float part[NH * MF];
    __shared__ float stabf[4];
    int tid = threadIdx.x;
    if (tid < NH * MF) part[tid] = 0.f;
    if (tid >= 128 && tid < 132) stabf[tid - 128] = decf(stab[tid - 128]);
    __syncthreads();
    int base = blockIdx.x * 64 * MF;   // 64 rows/block, exact: 1875*64 = 120000
    for (int i = tid; i < 64 * MF; i += 256) {
        int row = blockIdx.x * 64 + i / MF;
        int m = i - (i / MF) * MF;
        int h = row & 3;
        float v = RATIO * (expf(kp[base + i] - diagK[row] - stabf[h]) + 1e-6f);
        kp[base + i] = v;
        kp16[(size_t)row * 32 + m] = f2bf(v);
        atomicAdd(&part[h * MF + m], v);
    }
    if (tid < 64) {
        int row = blockIdx.x * 64 + tid;
        kp16[(size_t)row * 32 + 30] = 0;
        kp16[(size_t)row * 32 + 31] = 0;
    }
    __syncthreads();
    if (tid < NH * MF) atomicAdd(&kpsum[tid], part[tid]);
}

// ---------------- attn_norm[n,h] = qp[n,h,:] . kpsum[h,:] ----------------
__global__ __launch_bounds__(256) void k_an(const float* __restrict__ qp, const float* __restrict__ kpsum,
                                            float* __restrict__ an)
{
    __shared__ float kps[NH * MF];
    int tid = threadIdx.x;
    if (tid < NH * MF) kps[tid] = kpsum[tid];
    __syncthreads();
    int idx = blockIdx.x * 256 + tid;
    if (idx >= NN * NH) return;
    int h = idx & 3;
    const float* q = qp + (size_t)idx * MF;
    float s = 0.f;
    #pragma unroll
    for (int m = 0; m < MF; ++m) s += q[m] * kps[h * MF + m];
    an[idx] = s;
}

// ---------------- kvs via MFMA: kvs[h, km, d] = sum_n kg[n,km] * V[n,h,d] ----------------
#define KVS_CHUNKS 50
#define KVS_NPB (NN / KVS_CHUNKS)    /* 600 nodes per block */
__global__ __launch_bounds__(512) void k_kvs(const float* __restrict__ kp, const void* __restrict__ gum,
                                             const u16* __restrict__ V16, const int* __restrict__ flag,
                                             float* __restrict__ Pkvs, float* __restrict__ Pksum)
{
    __shared__ __align__(16) char kgT[320 * 128];   // 40KB bf16 [320 km][64 n] swizzled
    __shared__ __align__(16) char VT[64 * 128];     //  8KB bf16 [64 d][64 n] swizzled
    __shared__ float kpT[64][31];                    // +1 pad
    __shared__ float egT[64][10];
    const int tid = threadIdx.x;
    const int h = blockIdx.y;
    const int chunk = blockIdx.x;
    const int n0 = chunk * KVS_NPB;
    const int f32 = *flag;
    const int wave = tid >> 6, lane = tid & 63;

    float ksacc[5] = {0.f, 0.f, 0.f, 0.f, 0.f};
    f32x4 acc[10] = {};

    for (int t0 = 0; t0 < KVS_NPB; t0 += 64) {
        __syncthreads();   // prev-tile MFMA reads done
        // ---- stage kp tile (zero-pad past chunk end) ----
        for (int i = tid; i < 64 * MF; i += 512) {
            int n = i / MF, m = i - (i / MF) * MF;
            kpT[n][m] = (t0 + n < KVS_NPB) ? kp[(size_t)(n0 + t0 + n) * (NH * MF) + h * MF + m] : 0.f;
        }
        // ---- stage exp(gumbel) tile ----
        for (int i = tid; i < 64 * KG; i += 512) {
            int n = i / KG, k = i - (i / KG) * KG;
            float e = 0.f;
            if (t0 + n < KVS_NPB) {
                size_t gofs = (size_t)(n0 + t0 + n) * (NH * KG) + h * KG + k;
                float g = f32 ? ((const float*)gum)[gofs] : u2f(((const u16*)gum)[gofs]);
                e = expf(g);
            }
            egT[n][k] = e;
        }
        // ---- stage V^T tile (u16 scatter, swizzled) ----
        for (int i = tid; i < 64 * 16; i += 512) {
            int n = i >> 4, dq = (i & 15) * 4;
            u32 v0 = 0, v1 = 0;
            if (t0 + n < KVS_NPB) {
                uint2 vv = *(const uint2*)(V16 + (size_t)(n0 + t0 + n) * 256 + h * 64 + dq);
                v0 = vv.x; v1 = vv.y;
            }
            #pragma unroll
            for (int j = 0; j < 4; ++j) {
                u16 val = (u16)(((j < 2) ? v0 : v1) >> ((j & 1) * 16));
                int d = dq + j;
                *(u16*)(VT + d * 128 + ((n * 2) ^ ((d & 7) << 4))) = val;
            }
        }
        __syncthreads();
        // ---- build kgT = bf16(kp * eg); accumulate ksum from the rounded values ----
        #pragma unroll
        for (int it = 0; it < 5; ++it) {
            int idx = tid + it * 512;          // 2560 = 320 rows x 8 n-chunks
            int row = idx >> 3, nc = idx & 7;
            u32 w_[4] = {0u, 0u, 0u, 0u};
            if (row < 300) {
                int k = row / MF, m = row - (row / MF) * MF;
                float s = 0.f;
                #pragma unroll
                for (int p = 0; p < 4; ++p) {
                    int na = nc * 8 + 2 * p, nb = na + 1;
                    u16 ha = f2bf(kpT[na][m] * egT[na][k]);
                    u16 hb = f2bf(kpT[nb][m] * egT[nb][k]);
                    w_[p] = (u32)ha | ((u32)hb << 16);
                    s += u2f(ha) + u2f(hb);
                }
                ksacc[it] += s;
            }
            *(uint4*)(kgT + row * 128 + ((nc * 16) ^ ((row & 7) << 4))) = make_uint4(w_[0], w_[1], w_[2], w_[3]);
        }
        __syncthreads();
        // ---- MFMA: wave owns C-tiles ct = wave*10 + i; kt = ct/4 (km), dt = ct%4 (d) ----
        #pragma unroll
        for (int kk = 0; kk < 2; ++kk) {
            const int kb = (kk * 32 + ((lane >> 4) * 8)) * 2;
            #pragma unroll
            for (int i = 0; i < 10; ++i) {
                int ct = wave * 10 + i;
                int kt = ct >> 2, dt = ct & 3;
                int ar = kt * 16 + (lane & 15);
                bf16x8 a = *(const bf16x8*)(kgT + ar * 128 + (kb ^ ((ar & 7) << 4)));
                int br = dt * 16 + (lane & 15);
                bf16x8 b = *(const bf16x8*)(VT + br * 128 + (kb ^ ((br & 7) << 4)));
                acc[i] = __builtin_amdgcn_mfma_f32_16x16x32_bf16(a, b, acc[i], 0, 0, 0);
            }
        }
    }
    // ---- write Pkvs partials: [chunk][h][300][64] ----
    #pragma unroll
    for (int i = 0; i < 10; ++i) {
        int ct = wave * 10 + i;
        int kt = ct >> 2, dt = ct & 3;
        int col = dt * 16 + (lane & 15);
        #pragma unroll
        for (int r = 0; r < 4; ++r) {
            int row = kt * 16 + ((lane >> 4) * 4) + r;
            if (row < 300)
                Pkvs[(((size_t)chunk * NH + h) * 300 + row) * 64 + col] = acc[i][r];
        }
    }
    // ---- ksum partial: reduce across the 8 n-chunk threads of each row ----
    #pragma unroll
    for (int it = 0; it < 5; ++it) {
        float v = ksacc[it];
        v += __shfl_xor(v, 1);
        v += __shfl_xor(v, 2);
        v += __shfl_xor(v, 4);
        int row = (tid + it * 512) >> 3;
        if ((tid & 7) == 0 && row < 300)
            Pksum[chunk * 1200 + h * 300 + row] = v;
    }
}

// ---------------- reduce partials -> kvs, ksum ----------------
__global__ __launch_bounds__(256) void k_reduce(const float* __restrict__ Pkvs, const float* __restrict__ Pksum,
                                                float* __restrict__ kvs, float* __restrict__ ksum)
{
    int i = blockIdx.x * 256 + threadIdx.x;
    if (i < NH * KG * MF * DH) {
        float s = 0.f;
        for (int c = 0; c < KVS_CHUNKS; ++c) s += Pkvs[(size_t)c * (NH * 300 * 64) + i];
        kvs[i] = s;
    } else if (i < NH * KG * MF * DH + NH * KG * MF) {
        int j = i - NH * KG * MF * DH;
        float s = 0.f;
        for (int c = 0; c < KVS_CHUNKS; ++c) s += Pksum[c * 1200 + j];
        ksum[j] = s;
    }
}

// ---------------- per-edge attention weights -> link loss partials ----------------
__global__ __launch_bounds__(256) void k_edge(const int* __restrict__ ei,
                                              const u16* __restrict__ qp16, const u16* __restrict__ kp16,
                                              const float* __restrict__ an,
                                              const int* __restrict__ din, float* __restrict__ lossp)
{
    __shared__ float ls[64];
    int tid = threadIdx.x;
    int eg = tid >> 2, h = tid & 3;
    int e = blockIdx.x * 64 + eg;           // grid = NE/64 exact
    int s = ei[e], t = ei[NE + e];
    const uint4* qv = (const uint4*)(qp16 + ((size_t)t * NH + h) * 32);
    const uint4* kv = (const uint4*)(kp16 + ((size_t)s * NH + h) * 32);
    float num = 0.f;
    #pragma unroll
    for (int c = 0; c < 4; ++c) {
        uint4 a = qv[c], b = kv[c];
        num += u2f((u16)(a.x & 0xFFFF)) * u2f((u16)(b.x & 0xFFFF))
             + u2f((u16)(a.x >> 16))    * u2f((u16)(b.x >> 16))
             + u2f((u16)(a.y & 0xFFFF)) * u2f((u16)(b.y & 0xFFFF))
             + u2f((u16)(a.y >> 16))    * u2f((u16)(b.y >> 16))
             + u2f((u16)(a.z & 0xFFFF)) * u2f((u16)(b.z & 0xFFFF))
             + u2f((u16)(a.z >> 16))    * u2f((u16)(b.z >> 16))
             + u2f((u16)(a.w & 0xFFFF)) * u2f((u16)(b.w & 0xFFFF))
             + u2f((u16)(a.w >> 16))    * u2f((u16)(b.w >> 16));
    }
    float term = logf(num / an[(size_t)t * NH + h]);
    term += __shfl_xor(term, 1);
    term += __shfl_xor(term, 2);
    if (h == 0) ls[eg] = term / (float)din[t];
    __syncthreads();
    if (tid < 64) {
        float v = ls[tid];
        #pragma unroll
        for (int o = 32; o > 0; o >>= 1) v += __shfl_xor(v, o);
        if (tid == 0) atomicAdd(&lossp[blockIdx.x & 1023], v);
    }
}

// ---------------- attention readout: 48 nodes/block (3x16 sub-tiles) ----------------
#define AT_NT 48
__global__ __launch_bounds__(256) void k_attn(
    const float* __restrict__ qp, const float* __restrict__ kvs, const float* __restrict__ ksum,
    u16* __restrict__ zatt)
{
    __shared__ float qpTf[3][NH * 484];       // per 16-node sub-tile: plane h [m][j] stride 16
    __shared__ u32   kvbuf[NH * 964];         // bf16 kvs plane (stride 1928 u16); prologue alias: ksL fp32
    __shared__ float rdenL[3][16 * NH * KG];  // [sub][j][h][k]
    u16*   kvL16 = (u16*)kvbuf;
    float* ksL   = (float*)kvbuf;             // 1200 floats, dead before first kv stage
    int tid = threadIdx.x;
    int n0 = blockIdx.x * AT_NT;              // grid = NN/48 = 625 exact

    for (int i = tid; i < AT_NT * NH * MF; i += 256) {   // qp -> transposed LDS
        int j48 = i / (NH * MF); int r = i - j48 * (NH * MF);
        int h = r / MF; int m = r - h * MF;
        qpTf[j48 >> 4][h * 484 + m * 16 + (j48 & 15)] = qp[(size_t)(n0 + j48) * (NH * MF) + r];
    }
    for (int i = tid; i < NH * KG * MF; i += 256) ksL[i] = ksum[i];
    __syncthreads();
    for (int i = tid; i < AT_NT * NH * KG; i += 256) {   // rden = 1/(qp.ksum)
        int j48 = i / (NH * KG); int r = i - j48 * (NH * KG);
        int h = r / KG;
        int sub = j48 >> 4, j = j48 & 15;
        float s = 0.f;
        #pragma unroll
        for (int m = 0; m < MF; ++m) s += qpTf[sub][h * 484 + m * 16 + j] * ksL[r * MF + m];
        rdenL[sub][j * (NH * KG) + r] = 1.0f / s;
    }

    const int h  = tid >> 6;
    const int jg = (tid >> 4) & 3;
    const int dg = tid & 15;
    float acc[3][4][4] = {};
    for (int k = 0; k < KG; ++k) {
        __syncthreads();   // also protects ksL->kvL16 overlay on first iteration
        for (int i = tid; i < NH * MF * DH; i += 256) {  // stage kvs[:,k,:,:] as bf16
            int hh = i / (MF * DH); int r = i - hh * (MF * DH);
            kvL16[hh * 1928 + r] = f2bf(kvs[((size_t)(hh * 10 + k) * MF) * DH + r]);
        }
        __syncthreads();
        float ps[3][4][4] = {};
        const u16* kb = kvL16 + h * 1928 + dg * 4;
        const float* qb0 = qpTf[0] + h * 484 + jg * 4;
        const float* qb1 = qpTf[1] + h * 484 + jg * 4;
        const float* qb2 = qpTf[2] + h * 484 + jg * 4;
        #pragma unroll
        for (int m = 0; m < MF; ++m) {
            ushort4 bu = *(const ushort4*)(kb + m * 64);
            float4 b = make_float4(u2f(bu.x), u2f(bu.y), u2f(bu.z), u2f(bu.w));
            float4 a0 = *(const float4*)(qb0 + m * 16);
            float4 a1 = *(const float4*)(qb1 + m * 16);
            float4 a2 = *(const float4*)(qb2 + m * 16);
            ps[0][0][0] += a0.x * b.x; ps[0][0][1] += a0.x * b.y; ps[0][0][2] += a0.x * b.z; ps[0][0][3] += a0.x * b.w;
            ps[0][1][0] += a0.y * b.x; ps[0][1][1] += a0.y * b.y; ps[0][1][2] += a0.y * b.z; ps[0][1][3] += a0.y * b.w;
            ps[0][2][0] += a0.z * b.x; ps[0][2][1] += a0.z * b.y; ps[0][2][2] += a0.z * b.z; ps[0][2][3] += a0.z * b.w;
            ps[0][3][0] += a0.w * b.x; ps[0][3][1] += a0.w * b.y; ps[0][3][2] += a0.w * b.z; ps[0][3][3] += a0.w * b.w;
            ps[1][0][0] += a1.x * b.x; ps[1][0][1] += a1.x * b.y; ps[1][0][2] += a1.x * b.z; ps[1][0][3] += a1.x * b.w;
            ps[1][1][0] += a1.y * b.x; ps[1][1][1] += a1.y * b.y; ps[1][1][2] += a1.y * b.z; ps[1][1][3] += a1.y * b.w;
            ps[1][2][0] += a1.z * b.x; ps[1][2][1] += a1.z * b.y; ps[1][2][2] += a1.z * b.z; ps[1][2][3] += a1.z * b.w;
            ps[1][3][0] += a1.w * b.x; ps[1][3][1] += a1.w * b.y; ps[1][3][2] += a1.w * b.z; ps[1][3][3] += a1.w * b.w;
            ps[2][0][0] += a2.x * b.x; ps[2][0][1] += a2.x * b.y; ps[2][0][2] += a2.x * b.z; ps[2][0][3] += a2.x * b.w;
            ps[2][1][0] += a2.y * b.x; ps[2][1][1] += a2.y * b.y; ps[2][1][2] += a2.y * b.z; ps[2][1][3] += a2.y * b.w;
            ps[2][2][0] += a2.z * b.x; ps[2][2][1] += a2.z * b.y; ps[2][2][2] += a2.z * b.z; ps[2][2][3] += a2.z * b.w;
            ps[2][3][0] += a2.w * b.x; ps[2][3][1] += a2.w * b.y; ps[2][3][2] += a2.w * b.z; ps[2][3][3] += a2.w * b.w;
        }
        #pragma unroll
        for (int sub = 0; sub < 3; ++sub)
            #pragma unroll
            for (int j4 = 0; j4 < 4; ++j4) {
                float rd = rdenL[sub][(jg * 4 + j4) * (NH * KG) + h * KG + k];
                #pragma unroll
                for (int d4 = 0; d4 < 4; ++d4) acc[sub][j4][d4] += ps[sub][j4][d4] * rd;
            }
    }
    #pragma unroll
    for (int sub = 0; sub < 3; ++sub)
        #pragma unroll
        for (int j4 = 0; j4 < 4; ++j4) {
            int n = n0 + sub * 16 + jg * 4 + j4;
            #pragma unroll
            for (int d4 = 0; d4 < 4; ++d4)
                zatt[(size_t)n * 256 + h * 64 + dg * 4 + d4] = f2bf(acc[sub][j4][d4] * (1.0f / KG));
        }
}

// ---------------- conv gather: wave-per-node, zero barriers ----------------
__global__ __launch_bounds__(256) void k_gather(
    const u16* __restrict__ zatt, const u16* __restrict__ V16,
    const int* __restrict__ csr, const float* __restrict__ wedge,
    const int* __restrict__ offn, const int* __restrict__ din,
    const float* __restrict__ params, u16* __restrict__ pre)
{
    int tid = threadIdx.x;
    int w = tid >> 6, l = tid & 63;
    int n = blockIdx.x * 4 + w;             // grid = NN/4 = 7500 exact
    float sigb = 1.f / (1.f + expf(-params[P_BBF + (l >> 4)]));   // head of elems l*4..l*4+3
    int dn = din[n], o0 = offn[n];
    float c0 = 0.f, c1 = 0.f, c2 = 0.f, c3 = 0.f;
    for (int t0 = 0; t0 < dn; t0 += 64) {
        int cnt = min(64, dn - t0);
        int myIdx = 0; float myW = 0.f;
        if (l < cnt) { myIdx = csr[o0 + t0 + l]; myW = wedge[o0 + t0 + l]; }
        int j = 0;
        for (; j + 7 < cnt; j += 8) {       // 8 rows in flight (wave-uniform trip count)
            int   s0 = __shfl(myIdx, j),     s1 = __shfl(myIdx, j + 1);
            int   s2 = __shfl(myIdx, j + 2), s3 = __shfl(myIdx, j + 3);
            int   s4 = __shfl(myIdx, j + 4), s5 = __shfl(myIdx, j + 5);
            int   s6 = __shfl(myIdx, j + 6), s7 = __shfl(myIdx, j + 7);
            float w0 = __shfl(myW, j),     w1 = __shfl(myW, j + 1);
            float w2 = __shfl(myW, j + 2), w3 = __shfl(myW, j + 3);
            float w4 = __shfl(myW, j + 4), w5 = __shfl(myW, j + 5);
            float w6 = __shfl(myW, j + 6), w7 = __shfl(myW, j + 7);
            uint2 a0 = *(const uint2*)(V16 + (size_t)s0 * 256 + l * 4);
            uint2 a1 = *(const uint2*)(V16 + (size_t)s1 * 256 + l * 4);
            uint2 a2 = *(const uint2*)(V16 + (size_t)s2 * 256 + l * 4);
            uint2 a3 = *(const uint2*)(V16 + (size_t)s3 * 256 + l * 4);
            uint2 a4 = *(const uint2*)(V16 + (size_t)s4 * 256 + l * 4);
            uint2 a5 = *(const uint2*)(V16 + (size_t)s5 * 256 + l * 4);
            uint2 a6 = *(const uint2*)(V16 + (size_t)s6 * 256 + l * 4);
            uint2 a7 = *(const uint2*)(V16 + (size_t)s7 * 256 + l * 4);
            c0 += w0 * u2f((u16)(a0.x & 0xFFFF)) + w1 * u2f((u16)(a1.x & 0xFFFF))
                + w2 * u2f((u16)(a2.x & 0xFFFF)) + w3 * u2f((u16)(a3.x & 0xFFFF))
                + w4 * u2f((u16)(a4.x & 0xFFFF)) + w5 * u2f((u16)(a5.x & 0xFFFF))
                + w6 * u2f((u16)(a6.x & 0xFFFF)) + w7 * u2f((u16)(a7.x & 0xFFFF));
            c1 += w0 * u2f((u16)(a0.x >> 16)) + w1 * u2f((u16)(a1.x >> 16))
                + w2 * u2f((u16)(a2.x >> 16)) + w3 * u2f((u16)(a3.x >> 16))
                + w4 * u2f((u16)(a4.x >> 16)) + w5 * u2f((u16)(a5.x >> 16))
                + w6 * u2f((u16)(a6.x >> 16)) + w7 * u2f((u16)(a7.x >> 16));
            c2 += w0 * u2f((u16)(a0.y & 0xFFFF)) + w1 * u2f((u16)(a1.y & 0xFFFF))
                + w2 * u2f((u16)(a2.y & 0xFFFF)) + w3 * u2f((u16)(a3.y & 0xFFFF))
                + w4 * u2f((u16)(a4.y & 0xFFFF)) + w5 * u2f((u16)(a5.y & 0xFFFF))
                + w6 * u2f((u16)(a6.y & 0xFFFF)) + w7 * u2f((u16)(a7.y & 0xFFFF));
            c3 += w0 * u2f((u16)(a0.y >> 16)) + w1 * u2f((u16)(a1.y >> 16))
                + w2 * u2f((u16)(a2.y >> 16)) + w3 * u2f((u16)(a3.y >> 16))
                + w4 * u2f((u16)(a4.y >> 16)) + w5 * u2f((u16)(a5.y >> 16))
                + w6 * u2f((u16)(a6.y >> 16)) + w7 * u2f((u16)(a7.y >> 16));
        }
        for (; j < cnt; ++j) {
            int   s0 = __shfl(myIdx, j);
            float w0 = __shfl(myW, j);
            uint2 a0 = *(const uint2*)(V16 + (size_t)s0 * 256 + l * 4);
            c0 += w0 * u2f((u16)(a0.x & 0xFFFF));
            c1 += w0 * u2f((u16)(a0.x >> 16));
            c2 += w0 * u2f((u16)(a0.y & 0xFFFF));
            c3 += w0 * u2f((u16)(a0.y >> 16));
        }
    }
    uint2 za = *(const uint2*)(zatt + (size_t)n * 256 + l * 4);
    float e0 = u2f((u16)(za.x & 0xFFFF)) + sigb * c0;
    float e1 = u2f((u16)(za.x >> 16))    + sigb * c1;
    float e2 = u2f((u16)(za.y & 0xFFFF)) + sigb * c2;
    float e3 = u2f((u16)(za.y >> 16))    + sigb * c3;
    uint2 r;
    r.x = (u32)f2bf(e0) | ((u32)f2bf(e1) << 16);
    r.y = (u32)f2bf(e2) | ((u32)f2bf(e3) << 16);
    *(uint2*)(pre + (size_t)n * 256 + l * 4) = r;
}

// ---------------- out = pre(bf16) x Wo^T via MFMA (Wo hi/lo split on the fly) ----------------
__global__ __launch_bounds__(256) void k_out(
    const u16* __restrict__ pre, const float* __restrict__ params, float* __restrict__ out)
{
    __shared__ __align__(16) char smemc[24576];   // As(8KB) | BsH(8KB) | BsL(8KB)
    char* As  = smemc;
    char* BsH = smemc + 8192;
    char* BsL = smemc + 16384;
    const int tid = threadIdx.x;
    const int bm = blockIdx.x * 64;
    const int wave = tid >> 6, lane = tid & 63;
    const int wm = wave >> 1, wn = wave & 1;
    const int sr = tid >> 2;
    const int sc = (tid & 3) * 16;

    f32x4 acc[2][2] = {};

    for (int k0 = 0; k0 < 256; k0 += 64) {
        __syncthreads();
        int byt0 = sr * 128 + (((sc + 0) * 2) ^ ((sr & 7) << 4));
        int byt1 = sr * 128 + (((sc + 8) * 2) ^ ((sr & 7) << 4));
        {   // ---- stage A: pre rows (bf16 copy) ----
            int row = bm + sr;
            uint4 v0 = make_uint4(0, 0, 0, 0), v1 = v0;
            if (row < NN) {
                const uint4* p = (const uint4*)(pre + (size_t)row * 256 + k0 + sc);
                v0 = p[0]; v1 = p[1];
            }
            *(uint4*)(As + byt0) = v0;
            *(uint4*)(As + byt1) = v1;
        }
        {   // ---- stage B: Wo fp32 -> hi/lo bf16 planes ----
            float x[16];
            const float4* wr = (const float4*)(params + P_WOF + (size_t)sr * 256 + k0 + sc);
            #pragma unroll
            for (int q4 = 0; q4 < 4; ++q4) {
                float4 v = wr[q4];
                x[q4 * 4 + 0] = v.x; x[q4 * 4 + 1] = v.y;
                x[q4 * 4 + 2] = v.z; x[q4 * 4 + 3] = v.w;
            }
            #pragma unroll
            for (int j8 = 0; j8 < 2; ++j8) {
                u32 hw[4], lw[4];
                #pragma unroll
                for (int p = 0; p < 4; ++p) {
                    float a = x[j8 * 8 + 2 * p], b2 = x[j8 * 8 + 2 * p + 1];
                    u16 ha = f2bf(a), hb = f2bf(b2);
                    hw[p] = (u32)ha | ((u32)hb << 16);
                    u16 la = f2bf(a - u2f(ha)), lb = f2bf(b2 - u2f(hb));
                    lw[p] = (u32)la | ((u32)lb << 16);
                }
                int byt = sr * 128 + (((sc + j8 * 8) * 2) ^ ((sr & 7) << 4));
                *(uint4*)(BsH + byt) = make_uint4(hw[0], hw[1], hw[2], hw[3]);
                *(uint4*)(BsL + byt) = make_uint4(lw[0], lw[1], lw[2], lw[3]);
            }
        }
        __syncthreads();
        #pragma unroll
        for (int kk = 0; kk < 2; ++kk) {
            const int kb = (kk * 32 + ((lane >> 4) * 8)) * 2;
            bf16x8 a[2], bh[2], bl[2];
            #pragma unroll
            for (int i = 0; i < 2; ++i) {
                int ar = 32 * wm + 16 * i + (lane & 15);
                int ab = ar * 128 + (kb ^ ((ar & 7) << 4));
                a[i] = *(const bf16x8*)(As + ab);
                int br = 32 * wn + 16 * i + (lane & 15);
                int bb2 = br * 128 + (kb ^ ((br & 7) << 4));
                bh[i] = *(const bf16x8*)(BsH + bb2);
                bl[i] = *(const bf16x8*)(BsL + bb2);
            }
            #pragma unroll
            for (int i = 0; i < 2; ++i)
                #pragma unroll
                for (int nf = 0; nf < 2; ++nf) {
                    acc[i][nf] = __builtin_amdgcn_mfma_f32_16x16x32_bf16(a[i], bh[nf], acc[i][nf], 0, 0, 0);
                    acc[i][nf] = __builtin_amdgcn_mfma_f32_16x16x32_bf16(a[i], bl[nf], acc[i][nf], 0, 0, 0);
                }
        }
    }
    #pragma unroll
    for (int i = 0; i < 2; ++i)
        #pragma unroll
        for (int nf = 0; nf < 2; ++nf) {
            int col = 32 * wn + 16 * nf + (lane & 15);
            float bias = params[P_WOBF + col];
            #pragma unroll
            for (int r2 = 0; r2 < 4; ++r2) {
                int row = bm + 32 * wm + 16 * i + ((lane >> 4) * 4) + r2;
                if (row < NN) out[(size_t)row * 64 + col] = acc[i][nf][r2] + bias;
            }
        }
}

// ---------------- loss finalize ----------------
__global__ __launch_bounds__(256) void k_loss(const float* __restrict__ lossp, float* __restrict__ out) {
    __shared__ float s[256];
    int tid = threadIdx.x;
    float v = 0.f;
    for (int i = tid; i < 1024; i += 256) v += lossp[i];
    s[tid] = v;
    __syncthreads();
    for (int o = 128; o > 0; o >>= 1) {
        if (tid < o) s[tid] += s[tid + o];
        __syncthreads();
    }
    if (tid == 0) out[(size_t)NN * 64] = s[0] / (float)(NE * NH);   // fp32 output
}

extern "C" void kernel_launch(void* const* d_in, const int* in_sizes, int n_in,
                              void* d_out, int out_size, void* d_ws, size_t ws_size,
                              hipStream_t stream)
{
    const void* z    = d_in[0];
    const int*  ei   = (const int*)d_in[1];
    const void* taup = d_in[2];
    const void* gum  = d_in[3];
    const void* proj = d_in[4];
    const void* Wq   = d_in[5];
    const void* bq   = d_in[6];
    const void* Wk   = d_in[7];
    const void* bk   = d_in[8];
    const void* Wv   = d_in[9];
    const void* bv   = d_in[10];
    const void* Wo   = d_in[11];
    const void* Wob  = d_in[12];
    const void* bb   = d_in[13];
    float* out = (float*)d_out;

    // ---- workspace carve-up (fp32 units), total ~67 MB ----
    u16*   V16    = (u16*)d_ws;                    //  7,680,000 u16 : [N,256] bf16 V
    float* qpb    = (float*)d_ws + 3840000;        //  3,600,000 : [N,H,M]
    float* kpb    = qpb + (size_t)NN * NH * MF;    //  3,600,000 : dashK then kp in-place
    float* diagK  = kpb + (size_t)NN * NH * MF;    //    120,000
    float* anb    = diagK + (size_t)NN * NH;       //    120,000
    u16*   zatt   = (u16*)kpb;                     //  reuses kpb+diagK+anb (dead after k_edge)
    int*   csr    = (int*)(anb + (size_t)NN * NH); //    480,000
    int*   offn   = csr + NE;                      //     30,000
    float* params = (float*)(offn + NN);           //    215,749 (+pad to 215,752)
    // ---- zeroed accumulator region ----
    float* kvs    = params + 215752;               //     76,800 : [H,K,M,D]
    float* ksum   = kvs + NH * KG * MF * DH;       //      1,200 : [H,K,M]
    float* kpsum  = ksum + NH * KG * MF;           //        120 : [H,M]
    int*   din    = (int*)(kpsum + NH * MF);       //     30,000
    int*   doutd  = din + NN;                      //     30,000
    int*   fill   = doutd + NN;                    //     30,000
    int*   counter = fill + NN;                    //          4
    u32*   stab   = (u32*)(counter + 4);           //          4
    float* lossp  = (float*)(stab + 4);            //      1,024
    int*   flag   = (int*)(lossp + 1024);          //          4
    float* wedge  = (float*)(flag + 4);            //    480,000 (not zeroed; fully written)
    u16*   qp16   = (u16*)(wedge + NE);            //  3,840,000 u16 : [N,H,32] bf16 qp
    u16*   kp16   = qp16 + (size_t)NN * NH * 32;   //  3,840,000 u16 : [N,H,32] bf16 kp
    // kvs partials overlay qp16+kp16 (15.36 MB, exact fit: 50*4*300*64 floats);
    // alive only between k_kvs and k_reduce, after qp16/kp16's last reader (k_edge).
    float* Pkvs   = (float*)qp16;
    float* Pksum  = (float*)(kp16 + (size_t)NN * NH * 32);   //  60,000 floats (new tail)
    // W hi/lo bf16 planes overlay kp16 (dead until k_kp writes it, after k_gemm_feat)
    u16*   Whb    = kp16;                          //    196,608 u16 : [768][256] W hi
    u16*   Wlb    = kp16 + 196608;                 //    196,608 u16 : [768][256] W lo
    // pre[N,256] bf16 overlays qp16+kp16 (7,680,000 u16 exactly); alive only
    // between k_gather and k_out, after Pkvs's last reader (k_reduce).
    u16*   pre    = qp16;
    size_t zero_bytes = (size_t)((char*)(flag + 4) - (char*)kvs);

    hipMemsetAsync(kvs, 0, zero_bytes, stream);

    k_detect<<<dim3(1), dim3(64), 0, stream>>>((const u16*)z, flag);
    k_cvt_params<<<dim3((P_TOTAL + 255) / 256), dim3(256), 0, stream>>>(
        Wq, Wk, Wv, bq, bk, bv, Wo, Wob, bb, proj, taup, params, flag);
    k_cvt_w<<<dim3(768), dim3(256), 0, stream>>>(params, Whb, Wlb);

    k_deg <<<dim3((NE + 255) / 256), dim3(256), 0, stream>>>(ei, din, doutd);
    k_off <<<dim3((NN + 255) / 256), dim3(256), 0, stream>>>(din, offn, counter);
    k_fill<<<dim3((NE + 255) / 256), dim3(256), 0, stream>>>(ei, offn, fill, csr, din, doutd, wedge);
    k_gemm_feat<<<dim3((NN + 63) / 64), dim3(256), 0, stream>>>(
        z, params, flag, Whb, Wlb, V16, qpb, qp16, kpb, diagK, stab);
    k_kp  <<<dim3(NN * NH / 64), dim3(256), 0, stream>>>(kpb, diagK, stab, kpsum, kp16);
    k_an  <<<dim3((NN * NH + 255) / 256), dim3(256), 0, stream>>>(qpb, kpsum, anb);
    k_edge<<<dim3(NE / 64), dim3(256), 0, stream>>>(ei, qp16, kp16, anb, din, lossp);
    // qp16/kp16 dead from here; Pkvs overlays them (stream-ordered)
    k_kvs <<<dim3(KVS_CHUNKS, NH), dim3(512), 0, stream>>>(kpb, gum, V16, flag, Pkvs, Pksum);
    k_reduce<<<dim3((NH * KG * MF * DH + NH * KG * MF + 255) / 256), dim3(256), 0, stream>>>(
        Pkvs, Pksum, kvs, ksum);
    // zatt overwrites kpb/diagK/anb from here on (stream-ordered after their last readers)
    k_attn<<<dim3(NN / AT_NT), dim3(256), 0, stream>>>(qpb, kvs, ksum, zatt);
    // pre overlays qp16/kp16 (Pkvs dead after k_reduce)
    k_gather<<<dim3(NN / 4), dim3(256), 0, stream>>>(zatt, V16, csr, wedge, offn, din, params, pre);
    k_out<<<dim3((NN + 63) / 64), dim3(256), 0, stream>>>(pre, params, out);
    k_loss<<<dim3(1), dim3(256), 0, stream>>>(lossp, out);
}